// Round 12
// baseline (380.669 us; speedup 1.0000x reference)
//
#include <hip/hip_runtime.h>

typedef __attribute__((ext_vector_type(8))) short bh8;
typedef __attribute__((ext_vector_type(4))) short sh4;
typedef __attribute__((ext_vector_type(4))) float f4;
typedef __attribute__((ext_vector_type(16))) float f16v;
typedef __attribute__((ext_vector_type(4))) unsigned int u4;

__device__ __forceinline__ unsigned short f2bf(float x) {
  unsigned int u = __float_as_uint(x);
  u += 0x7fffu + ((u >> 16) & 1u);
  return (unsigned short)(u >> 16);
}
__device__ __forceinline__ float bf2f(short x) {
  return __uint_as_float(((unsigned int)(unsigned short)x) << 16);
}
__device__ __forceinline__ unsigned cvtpk_bf16(float lo, float hi) {
  unsigned r;
  asm("v_cvt_pk_bf16_f32 %0, %1, %2" : "=v"(r) : "v"(lo), "v"(hi));
  return r;
}
__device__ __forceinline__ void gl_lds16(const short* g, short* l) {
  __builtin_amdgcn_global_load_lds(
      (const __attribute__((address_space(1))) unsigned int*)g,
      (__attribute__((address_space(3))) unsigned int*)l, 16, 0, 0);
}

#define VM2() asm volatile("s_waitcnt vmcnt(2)" ::: "memory")
#define VM0() asm volatile("s_waitcnt vmcnt(0)" ::: "memory")

// ---------------- RoPE table ----------------
__global__ __launch_bounds__(256)
void rope_table(float* __restrict__ ct, float* __restrict__ st) {
  const int idx = blockIdx.x * 256 + threadIdx.x;   // 65536 = 2048*32
  const int s = idx >> 5, j = idx & 31;
  const float invf = expf(-0.28782313662425574f * (float)j);  // 10000^(-j/32)
  const float f = (float)s * invf;
  ct[idx] = cosf(f);
  st[idx] = sinf(f);
}

// ---------------- bias concat for fused QKV ----------------
__global__ __launch_bounds__(256)
void concat_bias(const float* __restrict__ bq, const float* __restrict__ bk,
                 const float* __restrict__ bv, float* __restrict__ bqkv) {
  const int i = blockIdx.x * 256 + threadIdx.x;  // 3072
  bqkv[i] = (i < 1024) ? bq[i] : ((i < 2048) ? bk[i - 1024] : bv[i - 2048]);
}

// ---------------- all weights fp32 -> bf16 (QKV concatenated) ----------------
__global__ __launch_bounds__(256)
void w2bf_all(const float* __restrict__ Wq, const float* __restrict__ Wk,
              const float* __restrict__ Wv, const float* __restrict__ Wo,
              const float* __restrict__ W1, const float* __restrict__ W2,
              short* __restrict__ wqkvb, short* __restrict__ wob,
              short* __restrict__ w1b, short* __restrict__ w2b) {
  const int which = blockIdx.y;
  const float* src; short* dst; int n;
  switch (which) {
    case 0: src = Wq; dst = wqkvb;                 n = 1 << 20; break;
    case 1: src = Wk; dst = wqkvb + (1 << 20);     n = 1 << 20; break;
    case 2: src = Wv; dst = wqkvb + (2 << 20);     n = 1 << 20; break;
    case 3: src = Wo; dst = wob;                   n = 1 << 20; break;
    case 4: src = W1; dst = w1b;                   n = 1 << 22; break;
    default: src = W2; dst = w2b;                  n = 1 << 22; break;
  }
  const int i = (blockIdx.x * 256 + threadIdx.x) * 4;
  if (i >= n) return;
  f4 v = *(const f4*)(src + i);
#pragma unroll
  for (int j = 0; j < 4; ++j) dst[i + j] = (short)f2bf(v[j]);
}

// ---------------- LayerNorm (row=1024) ----------------
__global__ __launch_bounds__(256)
void layernorm_bf(const float* __restrict__ x, const float* __restrict__ g,
                  const float* __restrict__ be, short* __restrict__ out) {
  __shared__ float sb[4];
  const int row = blockIdx.x, t = threadIdx.x;
  const float* xr = x + (size_t)row * 1024;
  f4 v = *(const f4*)(xr + t * 4);
  float s = v[0] + v[1] + v[2] + v[3];
#pragma unroll
  for (int mk = 1; mk < 64; mk <<= 1) s += __shfl_xor(s, mk, 64);
  if ((t & 63) == 0) sb[t >> 6] = s;
  __syncthreads();
  const float mean = (sb[0] + sb[1] + sb[2] + sb[3]) * (1.0f / 1024.0f);
  __syncthreads();
  f4 d;
#pragma unroll
  for (int i = 0; i < 4; ++i) d[i] = v[i] - mean;
  float s2 = d[0] * d[0] + d[1] * d[1] + d[2] * d[2] + d[3] * d[3];
#pragma unroll
  for (int mk = 1; mk < 64; mk <<= 1) s2 += __shfl_xor(s2, mk, 64);
  if ((t & 63) == 0) sb[t >> 6] = s2;
  __syncthreads();
  const float var = (sb[0] + sb[1] + sb[2] + sb[3]) * (1.0f / 1024.0f);
  const float rstd = rsqrtf(var + 1e-5f);
  const f4 gg = *(const f4*)(g + t * 4);
  const f4 bb = *(const f4*)(be + t * 4);
#pragma unroll
  for (int i = 0; i < 4; ++i)
    out[(size_t)row * 1024 + t * 4 + i] = (short)f2bf(d[i] * rstd * gg[i] + bb[i]);
}

// ---------------- triple-buffered BK=32 BM=BN=128 GEMM: 48KB LDS -> 3 blocks/CU ----------------
// Phase(t): ds_read 6 frags from buf[t%3]; stage tile t+2 -> buf[(t+2)%3] (its reads
// ended at phase t-1's end barrier -> race-free, r9 invariant); barrier; lgkm(0);
// 8 MFMA; VM2 (drains tile t+1, leaves tile t+2's 2 ops); barrier.
// Tail: no stage when t+2>=nkt; VM0 drains the rest. Swizzle slot^=(row&3) both-sides.
#define STG32(dst, gbase, kt)                                                  \
  gl_lds16(gbase + (size_t)sr32 * K + (kt) * 32 + ssl32 * 8, (dst) + t * 8);

#define PH32(Ac, Bc, STAGE_STMT, VMSTMT)                                       \
  {                                                                            \
    _Pragma("unroll") for (int j = 0; j < 4; ++j)                              \
      af[j] = *(const bh8*)(&(Ac)[(wm * 64 + j * 16 + (lane & 15)) * 32 + rslot]); \
    _Pragma("unroll") for (int ni = 0; ni < 2; ++ni)                           \
      bfrag[ni] = *(const bh8*)(&(Bc)[(wn * 32 + ni * 16 + (lane & 15)) * 32 + rslot]); \
    STAGE_STMT;                                                                \
    __builtin_amdgcn_s_barrier();                                              \
    asm volatile("s_waitcnt lgkmcnt(0)" ::: "memory");                         \
    __builtin_amdgcn_sched_barrier(0);                                         \
    __builtin_amdgcn_s_setprio(1);                                             \
    _Pragma("unroll") for (int j = 0; j < 4; ++j)                              \
    _Pragma("unroll") for (int ni = 0; ni < 2; ++ni)                           \
      acc[j][ni] = __builtin_amdgcn_mfma_f32_16x16x32_bf16(                    \
          af[j], bfrag[ni], acc[j][ni], 0, 0, 0);                              \
    __builtin_amdgcn_s_setprio(0);                                             \
    VMSTMT;                                                                    \
    __builtin_amdgcn_s_barrier();                                              \
  }

// QKVMODE: bn<16 -> q/k columns with fused RoPE; bn>=16 -> V columns stored
// transposed to Vt[b,h,d,s]. RoPE pairing: lane holds col c, partner col c^1
// lives in lane^1 (same row) -> one __shfl_xor(v,1). cos/sin from table.
template <int RELU, int RES, int OBF16, int QKVMODE>
__global__ __launch_bounds__(512, 6)
void gemm_tb(const short* __restrict__ A, const short* __restrict__ Bw,
             const float* __restrict__ bias, const float* __restrict__ res,
             const float* __restrict__ ct, const float* __restrict__ st,
             short* __restrict__ Vt,
             short* __restrict__ Cb, float* __restrict__ Cf,
             int M, int N, int K) {
  __shared__ short LA[3 * 4096];
  __shared__ short LB[3 * 4096];
  const int t = threadIdx.x, lane = t & 63;
  const int w = t >> 6, wm = w >> 2, wn = w & 3;
  const int nwg = gridDim.x, cpx = nwg >> 3;
  int flat = blockIdx.x;
  flat = (flat & 7) * cpx + (flat >> 3);
  const int nbn = N >> 7;
  const int bn = flat % nbn, bm = flat / nbn;   // bn-major: A panels XCD-local
  const short* Ab = A + (size_t)(bm * 128) * K;
  const short* Bb = Bw + (size_t)(bn * 128) * K;
  const int nkt = K >> 5;
  const int sr32 = t >> 2;                       // staging row 0..127
  const int ssl32 = (t & 3) ^ (sr32 & 3);        // pre-swizzled source slot
  const int rslot = (((lane >> 4) ^ (lane & 3)) << 3);  // read slot (row&3==lane&3)
  f4 acc[4][2] = {};
  bh8 bfrag[2], af[4];

  // prologue: t0(2 ops), t1(2 ops); VM2 drains t0, leaves t1
  STG32(LA, Ab, 0); STG32(LB, Bb, 0);
  STG32(&LA[4096], Ab, 1); STG32(&LB[4096], Bb, 1);
  VM2();
  __builtin_amdgcn_s_barrier();

  int cur = 0;
  for (int tt = 0; tt < nkt; ++tt) {
    const int stg = (cur >= 1) ? cur - 1 : 2;    // (cur+2)%3
    const bool sf = (tt + 2 < nkt);
    PH32(&LA[cur * 4096], &LB[cur * 4096],
         if (sf) { STG32(&LA[stg * 4096], Ab, tt + 2); STG32(&LB[stg * 4096], Bb, tt + 2); },
         if (sf) { VM2(); } else { VM0(); });
    cur = (cur >= 2) ? 0 : cur + 1;
  }

  const int rb = bm * 128 + wm * 64 + ((lane >> 4) << 2);
  const int cb = bn * 128 + wn * 32 + (lane & 15);
  if (QKVMODE && bn >= 16) {
    // V columns: transposed store into Vt[b,h,d,s] (4 s-consecutive per store)
#pragma unroll
    for (int mi = 0; mi < 4; ++mi) {
#pragma unroll
      for (int ni = 0; ni < 2; ++ni) {
        const int c = cb + ni * 16;
        const float bi = bias[c];
        const int hh = (c - 2048) >> 6, dd = (c - 2048) & 63;
        const int r0 = rb + mi * 16;
        const int bb2 = r0 >> 11, ss = r0 & 2047;
        sh4 pk;
#pragma unroll
        for (int jr = 0; jr < 4; ++jr) pk[jr] = (short)f2bf(acc[mi][ni][jr] + bi);
        *(sh4*)(Vt + ((size_t)(bb2 * 16 + hh) * 64 + dd) * 2048 + ss) = pk;
      }
    }
  } else if (QKVMODE) {
    // q/k columns: fused RoPE then bf16 store
    const bool evenc = (lane & 1) == 0;
#pragma unroll
    for (int mi = 0; mi < 4; ++mi) {
#pragma unroll
      for (int ni = 0; ni < 2; ++ni) {
        const int c = cb + ni * 16;
        const float bi = bias[c];
        const int j0 = (c & 63) >> 1;
#pragma unroll
        for (int jr = 0; jr < 4; ++jr) {
          const int r = rb + mi * 16 + jr;
          const int s = r & 2047;
          const float v = acc[mi][ni][jr] + bi;
          const float pv = __shfl_xor(v, 1, 64);   // partner column c^1, same row
          const float cs = ct[s * 32 + j0], sn = st[s * 32 + j0];
          const float o = evenc ? (v * cs - pv * sn) : (pv * sn + v * cs);
          Cb[(size_t)r * N + c] = (short)f2bf(o);
        }
      }
    }
  } else {
#pragma unroll
    for (int mi = 0; mi < 4; ++mi) {
#pragma unroll
      for (int ni = 0; ni < 2; ++ni) {
        const int c = cb + ni * 16;
        const float bi = bias[c];
#pragma unroll
        for (int jr = 0; jr < 4; ++jr) {
          const int r = rb + mi * 16 + jr;
          float v = acc[mi][ni][jr] + bi;
          if (RES) v += res[(size_t)r * N + c];
          if (RELU) v = fmaxf(v, 0.f);
          if (OBF16) Cb[(size_t)r * N + c] = (short)f2bf(v);
          else       Cf[(size_t)r * N + c] = v;
        }
      }
    }
  }
}

// ---------------- causal flash attention: 512 blocks, heavy/light CU-paired ----------------
__global__ __launch_bounds__(512, 4)
void flash_attn(const short* __restrict__ qkv, const short* __restrict__ vt,
                short* __restrict__ o) {
  __shared__ short lds[2 * 2 * 64 * 72];     // [buf][K|Vt][64][72]; reused as Ot[256][72]
  const int t = threadIdx.x, lane = t & 63, w = t >> 6;
  const int l31 = lane & 31, l5 = lane >> 5;
  const int id = blockIdx.x;
  const int half = id >> 8, j = id & 255;
  const int xcd = j & 7, y = j >> 3;
  const int bh = xcd * 8 + (y >> 2);
  const int pr = y & 3;
  const int qt = half ? pr : 7 - pr;
  const int b = bh >> 4, hh = bh & 15;
  const int r8 = t >> 3, c8 = (t & 7) * 8;
  const float NEG_INF = -__builtin_inff();

  const short* kbase = qkv + (size_t)b * 2048 * 3072 + 1024 + hh * 64;
  const short* vbase = vt + ((size_t)bh * 64 + r8) * 2048;
  const int wq0 = qt * 256 + w * 32;
  const int nt = 4 * qt + 4;

  bh8 qf[4];
  {
    const short* qrow = qkv + ((size_t)b * 2048 + wq0 + l31) * 3072 + hh * 64 + l5 * 8;
#pragma unroll
    for (int dk = 0; dk < 4; ++dk) qf[dk] = *(const bh8*)(qrow + dk * 16);
  }
  f16v o0 = {}, o1 = {};
  float mr = NEG_INF, lsum = 0.f;

  {
    bh8 rk = *(const bh8*)(kbase + (size_t)r8 * 3072 + c8);
    bh8 rv = *(const bh8*)(vbase + c8);
    *(bh8*)(&lds[r8 * 72 + c8]) = rk;
    *(bh8*)(&lds[4608 + r8 * 72 + c8]) = rv;
  }

  for (int kt = 0; kt < nt; ++kt) {
    __syncthreads();
    const int cur = kt & 1, nxt = cur ^ 1;
    bh8 rk, rv;
    const bool more = (kt + 1 < nt);
    if (more) {                             // issue next tile's loads early (T14)
      rk = *(const bh8*)(kbase + (size_t)((kt + 1) * 64 + r8) * 3072 + c8);
      rv = *(const bh8*)(vbase + (kt + 1) * 64 + c8);
    }
    const int kvb = kt * 64;
    if (kvb <= wq0 + 31) {
      const short* Kl = &lds[cur * 9216];
      const short* Vl = &lds[cur * 9216 + 4608];
      f16v s0 = {}, s1 = {};
#pragma unroll
      for (int dk = 0; dk < 4; ++dk) {
        bh8 ka0 = *(const bh8*)(&Kl[l31 * 72 + dk * 16 + l5 * 8]);
        bh8 ka1 = *(const bh8*)(&Kl[(32 + l31) * 72 + dk * 16 + l5 * 8]);
        s0 = __builtin_amdgcn_mfma_f32_32x32x16_bf16(ka0, qf[dk], s0, 0, 0, 0);
        s1 = __builtin_amdgcn_mfma_f32_32x32x16_bf16(ka1, qf[dk], s1, 0, 0, 0);
      }
      if (kvb + 63 > wq0) {
        const int qq = wq0 + l31;
        const int kvo = kvb + l5 * 4;
#pragma unroll
        for (int r = 0; r < 16; ++r) {
          const int kv0 = kvo + (r & 3) + 8 * (r >> 2);
          if (kv0 > qq) s0[r] = NEG_INF;
          if (kv0 + 32 > qq) s1[r] = NEG_INF;
        }
      }
      float mx = s0[0];
#pragma unroll
      for (int r = 1; r < 16; ++r) mx = fmaxf(mx, s0[r]);
#pragma unroll
      for (int r = 0; r < 16; ++r) mx = fmaxf(mx, s1[r]);
      mx = fmaxf(mx, __shfl_xor(mx, 32, 64));
      const bool keep = __all(mx <= mr + 8.0f);
      float mn, al;
      if (keep) { mn = mr; al = 1.0f; }
      else {
        mn = fmaxf(mr, mx);
        al = __expf((mr - mn) * 0.125f);
        mr = mn;
      }
      float rsA = 0.f, rsB = 0.f;
#pragma unroll
      for (int r = 0; r < 16; ++r) {
        const float p0 = __expf((s0[r] - mn) * 0.125f);
        const float p1 = __expf((s1[r] - mn) * 0.125f);
        s0[r] = p0; s1[r] = p1;
        rsA += p0; rsB += p1;
      }
      float rs = rsA + rsB;
      rs += __shfl_xor(rs, 32, 64);
      if (keep) {
        lsum += rs;
      } else {
        lsum = lsum * al + rs;
#pragma unroll
        for (int r = 0; r < 16; ++r) { o0[r] *= al; o1[r] *= al; }
      }
      float pp[32];
#pragma unroll
      for (int r = 0; r < 16; ++r) { pp[r] = s0[r]; pp[16 + r] = s1[r]; }
      const bool lo32 = (l5 == 0);
#pragma unroll
      for (int ks = 0; ks < 4; ++ks) {
        const int base = (ks >> 1) * 16 + (ks & 1) * 8;
        const unsigned e0 = cvtpk_bf16(pp[base + 0], pp[base + 1]);
        const unsigned e1 = cvtpk_bf16(pp[base + 2], pp[base + 3]);
        const unsigned q0 = cvtpk_bf16(pp[base + 4], pp[base + 5]);
        const unsigned q1 = cvtpk_bf16(pp[base + 6], pp[base + 7]);
        const unsigned sel0 = lo32 ? q0 : e0;
        const unsigned sel1 = lo32 ? q1 : e1;
        const unsigned rx0 = (unsigned)__shfl_xor((int)sel0, 32, 64);
        const unsigned rx1 = (unsigned)__shfl_xor((int)sel1, 32, 64);
        u4 frag;
        frag[0] = lo32 ? e0 : rx0;
        frag[1] = lo32 ? e1 : rx1;
        frag[2] = lo32 ? rx0 : q0;
        frag[3] = lo32 ? rx1 : q1;
        const bh8 pb = *(const bh8*)&frag;
        bh8 va0 = *(const bh8*)(&Vl[l31 * 72 + ks * 16 + l5 * 8]);
        bh8 va1 = *(const bh8*)(&Vl[(32 + l31) * 72 + ks * 16 + l5 * 8]);
        o0 = __builtin_amdgcn_mfma_f32_32x32x16_bf16(va0, pb, o0, 0, 0, 0);
        o1 = __builtin_amdgcn_mfma_f32_32x32x16_bf16(va1, pb, o1, 0, 0, 0);
      }
    }
    if (more) {
      *(bh8*)(&lds[nxt * 9216 + r8 * 72 + c8]) = rk;
      *(bh8*)(&lds[nxt * 9216 + 4608 + r8 * 72 + c8]) = rv;
    }
  }

  const float inv = 1.0f / lsum;
  __syncthreads();
  short* Ot = lds;
#pragma unroll
  for (int r = 0; r < 16; ++r) {
    const int d = (r & 3) + 8 * (r >> 2) + 4 * l5;
    Ot[(w * 32 + l31) * 72 + d]      = (short)f2bf(o0[r] * inv);
    Ot[(w * 32 + l31) * 72 + 32 + d] = (short)f2bf(o1[r] * inv);
  }
  __syncthreads();
  const int qrow = t >> 1, hf = t & 1;
  short* orow = o + ((size_t)b * 2048 + qt * 256 + qrow) * 1024 + hh * 64 + hf * 32;
#pragma unroll
  for (int i = 0; i < 4; ++i)
    *(bh8*)(orow + i * 8) = *(const bh8*)(&Ot[qrow * 72 + hf * 32 + i * 8]);
}

extern "C" void kernel_launch(void* const* d_in, const int* in_sizes, int n_in,
                              void* d_out, int out_size, void* d_ws, size_t ws_size,
                              hipStream_t stream) {
  const float* x   = (const float*)d_in[0];
  const float* Wq  = (const float*)d_in[1];
  const float* bq  = (const float*)d_in[2];
  const float* Wk  = (const float*)d_in[3];
  const float* bk  = (const float*)d_in[4];
  const float* Wv  = (const float*)d_in[5];
  const float* bv  = (const float*)d_in[6];
  const float* Wo  = (const float*)d_in[7];
  const float* bo  = (const float*)d_in[8];
  const float* W1  = (const float*)d_in[9];
  const float* bf1 = (const float*)d_in[10];
  const float* W2  = (const float*)d_in[11];
  const float* bf2 = (const float*)d_in[12];
  const float* g1  = (const float*)d_in[13];
  const float* be1 = (const float*)d_in[14];
  const float* g2  = (const float*)d_in[15];
  const float* be2 = (const float*)d_in[16];
  float* out = (float*)d_out;

  char* ws = (char*)d_ws;
  const size_t MB = 1u << 20;
  short* h_ob  = (short*)ws;                  // 16 MB: LN out; later attn out; later LN2 out
  short* qkv   = (short*)(ws + 16 * MB);      // 48 MB [8192][3072] (v-third unused)
  short* f1    = (short*)(ws + 16 * MB);      // 64 MB alias (qkv+vt, dead at FF time)
  short* vtb   = (short*)(ws + 64 * MB);      // 16 MB [bh][64][2048]
  short* wqkvb = (short*)(ws + 80 * MB);      // 6 MB
  short* wob   = (short*)(ws + 86 * MB);      // 2 MB
  short* w1b   = (short*)(ws + 88 * MB);      // 8 MB
  short* w2b   = (short*)(ws + 96 * MB);      // 8 MB
  float* ct    = (float*)(ws + 104 * MB);     // 256 KB
  float* st    = ct + 65536;                  // 256 KB
  float* bqkv  = st + 65536;                  // 12 KB
  float* x2    = out;

  rope_table<<<256, 256, 0, stream>>>(ct, st);
  concat_bias<<<12, 256, 0, stream>>>(bq, bk, bv, bqkv);
  w2bf_all<<<dim3(4096, 6), 256, 0, stream>>>(Wq, Wk, Wv, Wo, W1, W2,
                                              wqkvb, wob, w1b, w2b);

  layernorm_bf<<<8192, 256, 0, stream>>>(x, g1, be1, h_ob);

  // QKV: M=8192 N=3072 K=1024, fused RoPE (q/k) + transposed V store; grid 64*24
  gemm_tb<0, 0, 1, 1><<<1536, 512, 0, stream>>>(h_ob, wqkvb, bqkv, nullptr,
                                                ct, st, vtb, qkv, nullptr,
                                                8192, 3072, 1024);

  flash_attn<<<512, 512, 0, stream>>>(qkv, vtb, h_ob);

  // Wo: M=8192 N=1024 K=1024, +res, fp32 out; grid 64*8
  gemm_tb<0, 1, 0, 0><<<512, 512, 0, stream>>>(h_ob, wob, bo, x,
                                               nullptr, nullptr, nullptr,
                                               nullptr, x2, 8192, 1024, 1024);

  layernorm_bf<<<8192, 256, 0, stream>>>(x2, g2, be2, h_ob);

  // FF1: M=8192 N=4096 K=1024, relu, bf16 out; grid 64*32
  gemm_tb<1, 0, 1, 0><<<2048, 512, 0, stream>>>(h_ob, w1b, bf1, nullptr,
                                                nullptr, nullptr, nullptr,
                                                f1, nullptr, 8192, 4096, 1024);

  // FF2: M=8192 N=1024 K=4096, +res, fp32 out; grid 64*8
  gemm_tb<0, 1, 0, 0><<<512, 512, 0, stream>>>(f1, w2b, bf2, x2,
                                               nullptr, nullptr, nullptr,
                                               nullptr, out, 8192, 1024, 4096);
}

// Round 13
// 353.442 us; speedup vs baseline: 1.0770x; 1.0770x over previous
//
#include <hip/hip_runtime.h>

typedef __attribute__((ext_vector_type(8))) short bh8;
typedef __attribute__((ext_vector_type(4))) short sh4;
typedef __attribute__((ext_vector_type(4))) float f4;
typedef __attribute__((ext_vector_type(16))) float f16v;
typedef __attribute__((ext_vector_type(4))) unsigned int u4;

__device__ __forceinline__ unsigned short f2bf(float x) {
  unsigned int u = __float_as_uint(x);
  u += 0x7fffu + ((u >> 16) & 1u);
  return (unsigned short)(u >> 16);
}
__device__ __forceinline__ float bf2f(short x) {
  return __uint_as_float(((unsigned int)(unsigned short)x) << 16);
}
__device__ __forceinline__ unsigned cvtpk_bf16(float lo, float hi) {
  unsigned r;
  asm("v_cvt_pk_bf16_f32 %0, %1, %2" : "=v"(r) : "v"(lo), "v"(hi));
  return r;
}
__device__ __forceinline__ void gl_lds16(const short* g, short* l) {
  __builtin_amdgcn_global_load_lds(
      (const __attribute__((address_space(1))) unsigned int*)g,
      (__attribute__((address_space(3))) unsigned int*)l, 16, 0, 0);
}

#define VM4() asm volatile("s_waitcnt vmcnt(4)" ::: "memory")
#define VM2() asm volatile("s_waitcnt vmcnt(2)" ::: "memory")
#define VM0() asm volatile("s_waitcnt vmcnt(0)" ::: "memory")

// ---------------- RoPE table ----------------
__global__ __launch_bounds__(256)
void rope_table(float* __restrict__ ct, float* __restrict__ st) {
  const int idx = blockIdx.x * 256 + threadIdx.x;   // 65536 = 2048*32
  const int s = idx >> 5, j = idx & 31;
  const float invf = expf(-0.28782313662425574f * (float)j);  // 10000^(-j/32)
  const float f = (float)s * invf;
  ct[idx] = cosf(f);
  st[idx] = sinf(f);
}

// ---------------- bias concat for fused QKV ----------------
__global__ __launch_bounds__(256)
void concat_bias(const float* __restrict__ bq, const float* __restrict__ bk,
                 const float* __restrict__ bv, float* __restrict__ bqkv) {
  const int i = blockIdx.x * 256 + threadIdx.x;  // 3072
  bqkv[i] = (i < 1024) ? bq[i] : ((i < 2048) ? bk[i - 1024] : bv[i - 2048]);
}

// ---------------- all weights fp32 -> bf16 (QKV concatenated) ----------------
__global__ __launch_bounds__(256)
void w2bf_all(const float* __restrict__ Wq, const float* __restrict__ Wk,
              const float* __restrict__ Wv, const float* __restrict__ Wo,
              const float* __restrict__ W1, const float* __restrict__ W2,
              short* __restrict__ wqkvb, short* __restrict__ wob,
              short* __restrict__ w1b, short* __restrict__ w2b) {
  const int which = blockIdx.y;
  const float* src; short* dst; int n;
  switch (which) {
    case 0: src = Wq; dst = wqkvb;                 n = 1 << 20; break;
    case 1: src = Wk; dst = wqkvb + (1 << 20);     n = 1 << 20; break;
    case 2: src = Wv; dst = wqkvb + (2 << 20);     n = 1 << 20; break;
    case 3: src = Wo; dst = wob;                   n = 1 << 20; break;
    case 4: src = W1; dst = w1b;                   n = 1 << 22; break;
    default: src = W2; dst = w2b;                  n = 1 << 22; break;
  }
  const int i = (blockIdx.x * 256 + threadIdx.x) * 4;
  if (i >= n) return;
  f4 v = *(const f4*)(src + i);
#pragma unroll
  for (int j = 0; j < 4; ++j) dst[i + j] = (short)f2bf(v[j]);
}

// ---------------- LayerNorm (row=1024) ----------------
__global__ __launch_bounds__(256)
void layernorm_bf(const float* __restrict__ x, const float* __restrict__ g,
                  const float* __restrict__ be, short* __restrict__ out) {
  __shared__ float sb[4];
  const int row = blockIdx.x, t = threadIdx.x;
  const float* xr = x + (size_t)row * 1024;
  f4 v = *(const f4*)(xr + t * 4);
  float s = v[0] + v[1] + v[2] + v[3];
#pragma unroll
  for (int mk = 1; mk < 64; mk <<= 1) s += __shfl_xor(s, mk, 64);
  if ((t & 63) == 0) sb[t >> 6] = s;
  __syncthreads();
  const float mean = (sb[0] + sb[1] + sb[2] + sb[3]) * (1.0f / 1024.0f);
  __syncthreads();
  f4 d;
#pragma unroll
  for (int i = 0; i < 4; ++i) d[i] = v[i] - mean;
  float s2 = d[0] * d[0] + d[1] * d[1] + d[2] * d[2] + d[3] * d[3];
#pragma unroll
  for (int mk = 1; mk < 64; mk <<= 1) s2 += __shfl_xor(s2, mk, 64);
  if ((t & 63) == 0) sb[t >> 6] = s2;
  __syncthreads();
  const float var = (sb[0] + sb[1] + sb[2] + sb[3]) * (1.0f / 1024.0f);
  const float rstd = rsqrtf(var + 1e-5f);
  const f4 gg = *(const f4*)(g + t * 4);
  const f4 bb = *(const f4*)(be + t * 4);
#pragma unroll
  for (int i = 0; i < 4; ++i)
    out[(size_t)row * 1024 + t * 4 + i] = (short)f2bf(d[i] * rstd * gg[i] + bb[i]);
}

// ================= shared staging macro =================
#define STG(dst, gbase, kt, half)                                              \
  {                                                                            \
    _Pragma("unroll") for (int cc = 0; cc < 2; ++cc) {                         \
      const int rr = (half) * 128 + cc * 64 + sr;                              \
      gl_lds16(gbase + (size_t)rr * K + (kt) * 64 + ssl * 8,                   \
               &dst[rr * 64 + (t & 7) * 8]);                                   \
    }                                                                          \
  }

// ---------------- 4-sub-phase BM=128 BN=128 GEMM: 64KB LDS -> 2 blocks/CU ----------------
// Race-free staging invariant (r9 lesson): every STG targets a buffer whose reads
// ENDED at a barrier before the STG issues. Verified passing in r10/r11.
#define PH64(bf, q, STAGE_STMT, VMSTMT)                                        \
  {                                                                            \
    if ((q) == 0) {                                                            \
      _Pragma("unroll") for (int ni = 0; ni < 2; ++ni)                         \
      _Pragma("unroll") for (int kk = 0; kk < 2; ++kk)                         \
        bfrag[ni][kk] = *(const bh8*)(&Bs[bf][(wn * 32 + ni * 16 + (lane & 15)) * 64 + (((lane >> 4) + kk * 4) ^ (lane & 7)) * 8]); \
    }                                                                          \
    _Pragma("unroll") for (int j = 0; j < 2; ++j)                              \
    _Pragma("unroll") for (int kk = 0; kk < 2; ++kk)                           \
      af[j][kk] = *(const bh8*)(&As[bf][(wm * 64 + (2 * (q) + j) * 16 + (lane & 15)) * 64 + (((lane >> 4) + kk * 4) ^ (lane & 7)) * 8]); \
    STAGE_STMT;                                                                \
    __builtin_amdgcn_s_barrier();                                              \
    asm volatile("s_waitcnt lgkmcnt(0)" ::: "memory");                         \
    __builtin_amdgcn_sched_barrier(0);                                         \
    __builtin_amdgcn_s_setprio(1);                                             \
    _Pragma("unroll") for (int j = 0; j < 2; ++j)                              \
    _Pragma("unroll") for (int ni = 0; ni < 2; ++ni)                           \
    _Pragma("unroll") for (int kk = 0; kk < 2; ++kk)                           \
      acc[2 * (q) + j][ni] = __builtin_amdgcn_mfma_f32_16x16x32_bf16(          \
          af[j][kk], bfrag[ni][kk], acc[2 * (q) + j][ni], 0, 0, 0);            \
    __builtin_amdgcn_s_setprio(0);                                             \
    VMSTMT;                                                                    \
    __builtin_amdgcn_s_barrier();                                              \
  }

// QKVMODE: bn<16 -> q/k columns with fused RoPE (q additionally pre-scaled by
// 1/8 so flash softmax needs no scale); bn>=16 -> V stored transposed to Vt.
template <int RELU, int RES, int OBF16, int QKVMODE>
__global__ __launch_bounds__(512, 4)
void gemm_bn128(const short* __restrict__ A, const short* __restrict__ Bw,
                const float* __restrict__ bias, const float* __restrict__ res,
                const float* __restrict__ ct, const float* __restrict__ st,
                short* __restrict__ Vt,
                short* __restrict__ Cb, float* __restrict__ Cf,
                int M, int N, int K) {
  __shared__ short As[2][128 * 64];
  __shared__ short Bs[2][128 * 64];
  const int t = threadIdx.x, lane = t & 63;
  const int w = t >> 6, wm = w >> 2, wn = w & 3;
  const int nwg = gridDim.x, cpx = nwg >> 3;
  int flat = blockIdx.x;
  flat = (flat & 7) * cpx + (flat >> 3);
  const int nbn = N >> 7;
  const int bn = flat % nbn, bm = flat / nbn;   // bn-major: A panels XCD-local
  const short* Ab = A + (size_t)(bm * 128) * K;
  const short* Bb = Bw + (size_t)(bn * 128) * K;
  const int nkt = K >> 6;
  const int sr = t >> 3;
  const int ssl = (t & 7) ^ (sr & 7);
  f4 acc[4][2] = {};
  bh8 bfrag[2][2], af[2][2];

  // prologue: B0(2), A0(2), B1(2); VM2 drains B0,A0 (leaves B1)
  STG(Bs[0], Bb, 0, 0); STG(As[0], Ab, 0, 0);
  STG(Bs[1], Bb, 1, 0);
  VM2();
  __builtin_amdgcn_s_barrier();

  for (int i2 = 0; i2 < nkt; i2 += 2) {
    const bool nf = (i2 + 2 < nkt);
    PH64(0, 0, STG(As[1], Ab, i2 + 1, 0), );
    PH64(0, 1, if (nf) STG(Bs[0], Bb, i2 + 2, 0),
         if (nf) { VM2(); } else { VM0(); });
    PH64(1, 0, if (nf) STG(As[0], Ab, i2 + 2, 0), );
    PH64(1, 1, if (nf) STG(Bs[1], Bb, i2 + 3, 0), if (nf) { VM2(); });
  }

  const int rb = bm * 128 + wm * 64 + ((lane >> 4) << 2);
  const int cb = bn * 128 + wn * 32 + (lane & 15);
  if (QKVMODE && bn >= 16) {
    // V columns: transposed store into Vt[b,h,d,s] (4 s-consecutive per store)
#pragma unroll
    for (int mi = 0; mi < 4; ++mi) {
#pragma unroll
      for (int ni = 0; ni < 2; ++ni) {
        const int c = cb + ni * 16;
        const float bi = bias[c];
        const int hh = (c - 2048) >> 6, dd = (c - 2048) & 63;
        const int r0 = rb + mi * 16;
        const int bb2 = r0 >> 11, ss = r0 & 2047;
        sh4 pk;
#pragma unroll
        for (int jr = 0; jr < 4; ++jr) pk[jr] = (short)f2bf(acc[mi][ni][jr] + bi);
        *(sh4*)(Vt + ((size_t)(bb2 * 16 + hh) * 64 + dd) * 2048 + ss) = pk;
      }
    }
  } else if (QKVMODE) {
    // q/k columns: fused RoPE then bf16 store; q (bn<8) pre-scaled by 1/8
    const bool evenc = (lane & 1) == 0;
    const float qsc = (bn < 8) ? 0.125f : 1.0f;
#pragma unroll
    for (int mi = 0; mi < 4; ++mi) {
#pragma unroll
      for (int ni = 0; ni < 2; ++ni) {
        const int c = cb + ni * 16;
        const float bi = bias[c];
        const int j0 = (c & 63) >> 1;
#pragma unroll
        for (int jr = 0; jr < 4; ++jr) {
          const int r = rb + mi * 16 + jr;
          const int s = r & 2047;
          const float v = acc[mi][ni][jr] + bi;
          const float pv = __shfl_xor(v, 1, 64);   // partner column c^1, same row
          const float cs = ct[s * 32 + j0], sn = st[s * 32 + j0];
          const float o = (evenc ? (v * cs - pv * sn) : (pv * sn + v * cs)) * qsc;
          Cb[(size_t)r * N + c] = (short)f2bf(o);
        }
      }
    }
  } else {
#pragma unroll
    for (int mi = 0; mi < 4; ++mi) {
#pragma unroll
      for (int ni = 0; ni < 2; ++ni) {
        const int c = cb + ni * 16;
        const float bi = bias[c];
#pragma unroll
        for (int jr = 0; jr < 4; ++jr) {
          const int r = rb + mi * 16 + jr;
          float v = acc[mi][ni][jr] + bi;
          if (RES) v += res[(size_t)r * N + c];
          if (RELU) v = fmaxf(v, 0.f);
          if (OBF16) Cb[(size_t)r * N + c] = (short)f2bf(v);
          else       Cf[(size_t)r * N + c] = v;
        }
      }
    }
  }
}

// ---------------- 8-phase BM=256 BN=256 GEMM (r10-verified; used for FF1) ----------------
#define PH256(bf, q, STAGE_STMT, VMSTMT)                                       \
  {                                                                            \
    if ((q) == 0) {                                                            \
      _Pragma("unroll") for (int ni = 0; ni < 4; ++ni)                         \
      _Pragma("unroll") for (int kk = 0; kk < 2; ++kk)                         \
        bfrag[ni][kk] = *(const bh8*)(&Bs[bf][(wn * 64 + ni * 16 + (lane & 15)) * 64 + (((lane >> 4) + kk * 4) ^ (lane & 7)) * 8]); \
    }                                                                          \
    _Pragma("unroll") for (int j = 0; j < 2; ++j)                              \
    _Pragma("unroll") for (int kk = 0; kk < 2; ++kk)                           \
      af[j][kk] = *(const bh8*)(&As[bf][(wm * 128 + (2 * (q) + j) * 16 + (lane & 15)) * 64 + (((lane >> 4) + kk * 4) ^ (lane & 7)) * 8]); \
    STAGE_STMT;                                                                \
    __builtin_amdgcn_s_barrier();                                              \
    asm volatile("s_waitcnt lgkmcnt(0)" ::: "memory");                         \
    __builtin_amdgcn_sched_barrier(0);                                         \
    __builtin_amdgcn_s_setprio(1);                                             \
    _Pragma("unroll") for (int j = 0; j < 2; ++j)                              \
    _Pragma("unroll") for (int ni = 0; ni < 4; ++ni)                           \
    _Pragma("unroll") for (int kk = 0; kk < 2; ++kk)                           \
      acc[2 * (q) + j][ni] = __builtin_amdgcn_mfma_f32_16x16x32_bf16(          \
          af[j][kk], bfrag[ni][kk], acc[2 * (q) + j][ni], 0, 0, 0);            \
    __builtin_amdgcn_s_setprio(0);                                             \
    VMSTMT;                                                                    \
    __builtin_amdgcn_s_barrier();                                              \
  }

__global__ __launch_bounds__(512, 2)
void gemm256_ff1(const short* __restrict__ A, const short* __restrict__ Bw,
                 const float* __restrict__ bias, short* __restrict__ Cb,
                 int M, int N, int K) {
  __shared__ short As[2][256 * 64];
  __shared__ short Bs[2][256 * 64];
  const int t = threadIdx.x, lane = t & 63;
  const int w = t >> 6, wm = w >> 2, wn = w & 3;
  const int nwg = gridDim.x, cpx = nwg >> 3;
  int flat = blockIdx.x;
  flat = (flat & 7) * cpx + (flat >> 3);
  const int nbn = N >> 8;
  const int bn = flat % nbn, bm = flat / nbn;   // bn-major
  const short* Ab = A + (size_t)(bm * 256) * K;
  const short* Bb = Bw + (size_t)(bn * 256) * K;
  const int nkt = K >> 6;
  const int sr = t >> 3;
  const int ssl = (t & 7) ^ (sr & 7);
  f4 acc[8][4] = {};
  bh8 bfrag[4][2], af[2][2];

  STG(Bs[0], Bb, 0, 0); STG(Bs[0], Bb, 0, 1);
  STG(As[0], Ab, 0, 0); STG(As[0], Ab, 0, 1);
  STG(Bs[1], Bb, 1, 0); STG(Bs[1], Bb, 1, 1);
  VM4();
  __builtin_amdgcn_s_barrier();

  for (int i2 = 0; i2 < nkt; i2 += 2) {
    const bool nf = (i2 + 2 < nkt);
    PH256(0, 0, STG(As[1], Ab, i2 + 1, 0), );
    PH256(0, 1, STG(As[1], Ab, i2 + 1, 1), );
    PH256(0, 2, if (nf) STG(Bs[0], Bb, i2 + 2, 0), );
    PH256(0, 3, if (nf) STG(Bs[0], Bb, i2 + 2, 1),
          if (nf) { VM4(); } else { VM0(); });
    PH256(1, 0, if (nf) STG(As[0], Ab, i2 + 2, 0), );
    PH256(1, 1, if (nf) STG(As[0], Ab, i2 + 2, 1), );
    PH256(1, 2, if (nf) STG(Bs[1], Bb, i2 + 3, 0), );
    PH256(1, 3, if (nf) STG(Bs[1], Bb, i2 + 3, 1), if (nf) { VM4(); });
  }

  const int rb = bm * 256 + wm * 128 + ((lane >> 4) << 2);
  const int cb = bn * 256 + wn * 64 + (lane & 15);
#pragma unroll
  for (int mi = 0; mi < 8; ++mi) {
#pragma unroll
    for (int ni = 0; ni < 4; ++ni) {
      const int c = cb + ni * 16;
      const float bi = bias[c];
#pragma unroll
      for (int jr = 0; jr < 4; ++jr) {
        const int r = rb + mi * 16 + jr;
        Cb[(size_t)r * N + c] = (short)f2bf(fmaxf(acc[mi][ni][jr] + bi, 0.f));
      }
    }
  }
}

// ---------------- causal flash attention: 256-thr / 128-q-row blocks, 4/CU ----------------
// 4 warps x 32 q-rows, 32x32 MFMA, swapped QK^T, in-register softmax, defer-max.
// Q pre-scaled by 1/8 in the QKV epilogue -> no scale in the softmax path.
// Grid 1024: half=id>>9 selects heavy(15-pr)/light(pr) qt; ids j and j+256 of both
// halves co-reside per CU -> uniform 68 steps/CU.
__global__ __launch_bounds__(256, 4)
void flash_attn(const short* __restrict__ qkv, const short* __restrict__ vt,
                short* __restrict__ o) {
  __shared__ short lds[2 * 2 * 64 * 72];     // [buf][K|Vt][64][72]; reused as Ot[128][72]
  const int t = threadIdx.x, lane = t & 63, w = t >> 6;   // w 0..3
  const int l31 = lane & 31, l5 = lane >> 5;
  const int id = blockIdx.x;
  const int half = id >> 9, j = id & 511;
  const int xcd = j & 7, y = j >> 3;         // y 0..63
  const int bh = xcd * 8 + (y >> 3);
  const int pr = y & 7;
  const int qt = half ? pr : 15 - pr;        // 128-row q tile, 0..15
  const int b = bh >> 4, hh = bh & 15;
  const int r8 = t >> 3, c8 = (t & 7) * 8;   // r8 0..31
  const float NEG_INF = -__builtin_inff();

  const short* kbase = qkv + (size_t)b * 2048 * 3072 + 1024 + hh * 64;
  const short* vbase = vt + (size_t)bh * 64 * 2048;
  const int wq0 = qt * 128 + w * 32;
  const int nt = 2 * qt + 2;

  bh8 qf[4];
  {
    const short* qrow = qkv + ((size_t)b * 2048 + wq0 + l31) * 3072 + hh * 64 + l5 * 8;
#pragma unroll
    for (int dk = 0; dk < 4; ++dk) qf[dk] = *(const bh8*)(qrow + dk * 16);
  }
  f16v o0 = {}, o1 = {};
  float mr = NEG_INF, lsum = 0.f;

  bh8 rk[2], rv[2];
#pragma unroll
  for (int p = 0; p < 2; ++p) {
    rk[p] = *(const bh8*)(kbase + (size_t)(p * 32 + r8) * 3072 + c8);
    rv[p] = *(const bh8*)(vbase + (size_t)(p * 32 + r8) * 2048 + c8);
  }
#pragma unroll
  for (int p = 0; p < 2; ++p) {
    *(bh8*)(&lds[(p * 32 + r8) * 72 + c8]) = rk[p];
    *(bh8*)(&lds[4608 + (p * 32 + r8) * 72 + c8]) = rv[p];
  }

  for (int kt = 0; kt < nt; ++kt) {
    __syncthreads();
    const int cur = kt & 1, nxt = cur ^ 1;
    const bool more = (kt + 1 < nt);
    if (more) {                              // issue next tile's loads early (T14)
#pragma unroll
      for (int p = 0; p < 2; ++p) {
        rk[p] = *(const bh8*)(kbase + (size_t)((kt + 1) * 64 + p * 32 + r8) * 3072 + c8);
        rv[p] = *(const bh8*)(vbase + (size_t)(p * 32 + r8) * 2048 + (kt + 1) * 64 + c8);
      }
    }
    const int kvb = kt * 64;
    if (kvb <= wq0 + 31) {
      const short* Kl = &lds[cur * 9216];
      const short* Vl = &lds[cur * 9216 + 4608];
      f16v s0 = {}, s1 = {};
#pragma unroll
      for (int dk = 0; dk < 4; ++dk) {
        bh8 ka0 = *(const bh8*)(&Kl[l31 * 72 + dk * 16 + l5 * 8]);
        bh8 ka1 = *(const bh8*)(&Kl[(32 + l31) * 72 + dk * 16 + l5 * 8]);
        s0 = __builtin_amdgcn_mfma_f32_32x32x16_bf16(ka0, qf[dk], s0, 0, 0, 0);
        s1 = __builtin_amdgcn_mfma_f32_32x32x16_bf16(ka1, qf[dk], s1, 0, 0, 0);
      }
      if (kvb + 63 > wq0) {
        const int qq = wq0 + l31;
        const int kvo = kvb + l5 * 4;
#pragma unroll
        for (int r = 0; r < 16; ++r) {
          const int kv0 = kvo + (r & 3) + 8 * (r >> 2);
          if (kv0 > qq) s0[r] = NEG_INF;
          if (kv0 + 32 > qq) s1[r] = NEG_INF;
        }
      }
      float mx = s0[0];
#pragma unroll
      for (int r = 1; r < 16; ++r) mx = fmaxf(mx, s0[r]);
#pragma unroll
      for (int r = 0; r < 16; ++r) mx = fmaxf(mx, s1[r]);
      mx = fmaxf(mx, __shfl_xor(mx, 32, 64));
      const bool keep = __all(mx <= mr + 8.0f);   // T13 defer-max, THR=8 (scaled)
      float mn, al;
      if (keep) { mn = mr; al = 1.0f; }
      else {
        mn = fmaxf(mr, mx);
        al = __expf(mr - mn);
        mr = mn;
      }
      float rsA = 0.f, rsB = 0.f;
#pragma unroll
      for (int r = 0; r < 16; ++r) {
        const float p0 = __expf(s0[r] - mn);
        const float p1 = __expf(s1[r] - mn);
        s0[r] = p0; s1[r] = p1;
        rsA += p0; rsB += p1;
      }
      float rs = rsA + rsB;
      rs += __shfl_xor(rs, 32, 64);
      if (keep) {
        lsum += rs;
      } else {
        lsum = lsum * al + rs;
#pragma unroll
        for (int r = 0; r < 16; ++r) { o0[r] *= al; o1[r] *= al; }
      }
      float pp[32];
#pragma unroll
      for (int r = 0; r < 16; ++r) { pp[r] = s0[r]; pp[16 + r] = s1[r]; }
      const bool lo32 = (l5 == 0);
#pragma unroll
      for (int ks = 0; ks < 4; ++ks) {
        const int base = (ks >> 1) * 16 + (ks & 1) * 8;
        const unsigned e0 = cvtpk_bf16(pp[base + 0], pp[base + 1]);
        const unsigned e1 = cvtpk_bf16(pp[base + 2], pp[base + 3]);
        const unsigned q0 = cvtpk_bf16(pp[base + 4], pp[base + 5]);
        const unsigned q1 = cvtpk_bf16(pp[base + 6], pp[base + 7]);
        const unsigned sel0 = lo32 ? q0 : e0;
        const unsigned sel1 = lo32 ? q1 : e1;
        const unsigned rx0 = (unsigned)__shfl_xor((int)sel0, 32, 64);
        const unsigned rx1 = (unsigned)__shfl_xor((int)sel1, 32, 64);
        u4 frag;
        frag[0] = lo32 ? e0 : rx0;
        frag[1] = lo32 ? e1 : rx1;
        frag[2] = lo32 ? rx0 : q0;
        frag[3] = lo32 ? rx1 : q1;
        const bh8 pb = *(const bh8*)&frag;
        bh8 va0 = *(const bh8*)(&Vl[l31 * 72 + ks * 16 + l5 * 8]);
        bh8 va1 = *(const bh8*)(&Vl[(32 + l31) * 72 + ks * 16 + l5 * 8]);
        o0 = __builtin_amdgcn_mfma_f32_32x32x16_bf16(va0, pb, o0, 0, 0, 0);
        o1 = __builtin_amdgcn_mfma_f32_32x32x16_bf16(va1, pb, o1, 0, 0, 0);
      }
    }
    if (more) {
#pragma unroll
      for (int p = 0; p < 2; ++p) {
        *(bh8*)(&lds[nxt * 9216 + (p * 32 + r8) * 72 + c8]) = rk[p];
        *(bh8*)(&lds[nxt * 9216 + 4608 + (p * 32 + r8) * 72 + c8]) = rv[p];
      }
    }
  }

  const float inv = 1.0f / lsum;
  __syncthreads();
  short* Ot = lds;                            // [128][72]
#pragma unroll
  for (int r = 0; r < 16; ++r) {
    const int d = (r & 3) + 8 * (r >> 2) + 4 * l5;
    Ot[(w * 32 + l31) * 72 + d]      = (short)f2bf(o0[r] * inv);
    Ot[(w * 32 + l31) * 72 + 32 + d] = (short)f2bf(o1[r] * inv);
  }
  __syncthreads();
  const int qrow = t >> 1, hf = t & 1;        // 128 rows x 2 halves
  short* orow = o + ((size_t)b * 2048 + qt * 128 + qrow) * 1024 + hh * 64 + hf * 32;
#pragma unroll
  for (int i = 0; i < 4; ++i)
    *(bh8*)(orow + i * 8) = *(const bh8*)(&Ot[qrow * 72 + hf * 32 + i * 8]);
}

extern "C" void kernel_launch(void* const* d_in, const int* in_sizes, int n_in,
                              void* d_out, int out_size, void* d_ws, size_t ws_size,
                              hipStream_t stream) {
  const float* x   = (const float*)d_in[0];
  const float* Wq  = (const float*)d_in[1];
  const float* bq  = (const float*)d_in[2];
  const float* Wk  = (const float*)d_in[3];
  const float* bk  = (const float*)d_in[4];
  const float* Wv  = (const float*)d_in[5];
  const float* bv  = (const float*)d_in[6];
  const float* Wo  = (const float*)d_in[7];
  const float* bo  = (const float*)d_in[8];
  const float* W1  = (const float*)d_in[9];
  const float* bf1 = (const float*)d_in[10];
  const float* W2  = (const float*)d_in[11];
  const float* bf2 = (const float*)d_in[12];
  const float* g1  = (const float*)d_in[13];
  const float* be1 = (const float*)d_in[14];
  const float* g2  = (const float*)d_in[15];
  const float* be2 = (const float*)d_in[16];
  float* out = (float*)d_out;

  char* ws = (char*)d_ws;
  const size_t MB = 1u << 20;
  short* h_ob  = (short*)ws;                  // 16 MB: LN out; later attn out; later LN2 out
  short* qkv   = (short*)(ws + 16 * MB);      // 48 MB [8192][3072] (v-third unused)
  short* f1    = (short*)(ws + 16 * MB);      // 64 MB alias (qkv+vt, dead at FF time)
  short* vtb   = (short*)(ws + 64 * MB);      // 16 MB [bh][64][2048]
  short* wqkvb = (short*)(ws + 80 * MB);      // 6 MB
  short* wob   = (short*)(ws + 86 * MB);      // 2 MB
  short* w1b   = (short*)(ws + 88 * MB);      // 8 MB
  short* w2b   = (short*)(ws + 96 * MB);      // 8 MB
  float* ct    = (float*)(ws + 104 * MB);     // 256 KB
  float* st    = ct + 65536;                  // 256 KB
  float* bqkv  = st + 65536;                  // 12 KB
  float* x2    = out;

  rope_table<<<256, 256, 0, stream>>>(ct, st);
  concat_bias<<<12, 256, 0, stream>>>(bq, bk, bv, bqkv);
  w2bf_all<<<dim3(4096, 6), 256, 0, stream>>>(Wq, Wk, Wv, Wo, W1, W2,
                                              wqkvb, wob, w1b, w2b);

  layernorm_bf<<<8192, 256, 0, stream>>>(x, g1, be1, h_ob);

  // QKV: fused RoPE (q pre-scaled 1/8) + transposed V store; grid 64*24
  gemm_bn128<0, 0, 1, 1><<<1536, 512, 0, stream>>>(h_ob, wqkvb, bqkv, nullptr,
                                                   ct, st, vtb, qkv, nullptr,
                                                   8192, 3072, 1024);

  flash_attn<<<1024, 256, 0, stream>>>(qkv, vtb, h_ob);

  // Wo: +res, fp32 out; grid 64*8
  gemm_bn128<0, 1, 0, 0><<<512, 512, 0, stream>>>(h_ob, wob, bo, x,
                                                  nullptr, nullptr, nullptr,
                                                  nullptr, x2, 8192, 1024, 1024);

  layernorm_bf<<<8192, 256, 0, stream>>>(x2, g2, be2, h_ob);

  // FF1: 256^2 8-phase, relu, bf16 out; grid 32*16
  gemm256_ff1<<<512, 512, 0, stream>>>(h_ob, w1b, bf1, f1, 8192, 4096, 1024);

  // FF2: +res, fp32 out; grid 64*8
  gemm_bn128<0, 1, 0, 0><<<512, 512, 0, stream>>>(f1, w2b, bf2, x2,
                                                  nullptr, nullptr, nullptr,
                                                  nullptr, out, 8192, 1024, 4096);
}

// Round 14
// 349.715 us; speedup vs baseline: 1.0885x; 1.0107x over previous
//
#include <hip/hip_runtime.h>

typedef __attribute__((ext_vector_type(8))) short bh8;
typedef __attribute__((ext_vector_type(4))) short sh4;
typedef __attribute__((ext_vector_type(4))) float f4;
typedef __attribute__((ext_vector_type(16))) float f16v;
typedef __attribute__((ext_vector_type(4))) unsigned int u4;

__device__ __forceinline__ unsigned short f2bf(float x) {
  unsigned int u = __float_as_uint(x);
  u += 0x7fffu + ((u >> 16) & 1u);
  return (unsigned short)(u >> 16);
}
__device__ __forceinline__ float bf2f(short x) {
  return __uint_as_float(((unsigned int)(unsigned short)x) << 16);
}
__device__ __forceinline__ unsigned cvtpk_bf16(float lo, float hi) {
  unsigned r;
  asm("v_cvt_pk_bf16_f32 %0, %1, %2" : "=v"(r) : "v"(lo), "v"(hi));
  return r;
}
__device__ __forceinline__ void gl_lds16(const short* g, short* l) {
  __builtin_amdgcn_global_load_lds(
      (const __attribute__((address_space(1))) unsigned int*)g,
      (__attribute__((address_space(3))) unsigned int*)l, 16, 0, 0);
}

#define VM4() asm volatile("s_waitcnt vmcnt(4)" ::: "memory")
#define VM2() asm volatile("s_waitcnt vmcnt(2)" ::: "memory")
#define VM0() asm volatile("s_waitcnt vmcnt(0)" ::: "memory")

// ---------------- fused prologue: RoPE table + bias concat + all weight bf16 casts ----------------
// blocks: [0,256) rope table; [256,268) bias concat; [268,268+12288) weight casts
__global__ __launch_bounds__(256)
void prep_all(const float* __restrict__ Wq, const float* __restrict__ Wk,
              const float* __restrict__ Wv, const float* __restrict__ Wo,
              const float* __restrict__ W1, const float* __restrict__ W2,
              const float* __restrict__ bq, const float* __restrict__ bk,
              const float* __restrict__ bv,
              short* __restrict__ wqkvb, short* __restrict__ wob,
              short* __restrict__ w1b, short* __restrict__ w2b,
              float* __restrict__ ct, float* __restrict__ st,
              float* __restrict__ bqkv) {
  const int t = threadIdx.x;
  int blk = blockIdx.x;
  if (blk < 256) {                    // rope cos/sin table (65536 entries)
    const int idx = blk * 256 + t;
    const int s = idx >> 5, j = idx & 31;
    const float invf = expf(-0.28782313662425574f * (float)j);  // 10000^(-j/32)
    const float f = (float)s * invf;
    ct[idx] = cosf(f);
    st[idx] = sinf(f);
    return;
  }
  blk -= 256;
  if (blk < 12) {                     // bias concat (3072 entries)
    const int i = blk * 256 + t;
    bqkv[i] = (i < 1024) ? bq[i] : ((i < 2048) ? bk[i - 1024] : bv[i - 2048]);
    return;
  }
  blk -= 12;
  const float* src; short* dst; int base;
  if (blk < 4096) {
    const int m = blk >> 10;
    src = (m == 0) ? Wq : (m == 1) ? Wk : (m == 2) ? Wv : Wo;
    dst = (m < 3) ? (wqkvb + (m << 20)) : wob;
    base = blk & 1023;
  } else if (blk < 8192) {
    src = W1; dst = w1b; base = blk - 4096;
  } else {
    src = W2; dst = w2b; base = blk - 8192;
  }
  const int i = (base * 256 + t) * 4;
  f4 v = *(const f4*)(src + i);
#pragma unroll
  for (int j = 0; j < 4; ++j) dst[i + j] = (short)f2bf(v[j]);
}

// ---------------- LayerNorm (row=1024) ----------------
__global__ __launch_bounds__(256)
void layernorm_bf(const float* __restrict__ x, const float* __restrict__ g,
                  const float* __restrict__ be, short* __restrict__ out) {
  __shared__ float sb[4];
  const int row = blockIdx.x, t = threadIdx.x;
  const float* xr = x + (size_t)row * 1024;
  f4 v = *(const f4*)(xr + t * 4);
  float s = v[0] + v[1] + v[2] + v[3];
#pragma unroll
  for (int mk = 1; mk < 64; mk <<= 1) s += __shfl_xor(s, mk, 64);
  if ((t & 63) == 0) sb[t >> 6] = s;
  __syncthreads();
  const float mean = (sb[0] + sb[1] + sb[2] + sb[3]) * (1.0f / 1024.0f);
  __syncthreads();
  f4 d;
#pragma unroll
  for (int i = 0; i < 4; ++i) d[i] = v[i] - mean;
  float s2 = d[0] * d[0] + d[1] * d[1] + d[2] * d[2] + d[3] * d[3];
#pragma unroll
  for (int mk = 1; mk < 64; mk <<= 1) s2 += __shfl_xor(s2, mk, 64);
  if ((t & 63) == 0) sb[t >> 6] = s2;
  __syncthreads();
  const float var = (sb[0] + sb[1] + sb[2] + sb[3]) * (1.0f / 1024.0f);
  const float rstd = rsqrtf(var + 1e-5f);
  const f4 gg = *(const f4*)(g + t * 4);
  const f4 bb = *(const f4*)(be + t * 4);
#pragma unroll
  for (int i = 0; i < 4; ++i)
    out[(size_t)row * 1024 + t * 4 + i] = (short)f2bf(d[i] * rstd * gg[i] + bb[i]);
}

// ================= shared staging macro =================
#define STG(dst, gbase, kt, half)                                              \
  {                                                                            \
    _Pragma("unroll") for (int cc = 0; cc < 2; ++cc) {                         \
      const int rr = (half) * 128 + cc * 64 + sr;                              \
      gl_lds16(gbase + (size_t)rr * K + (kt) * 64 + ssl * 8,                   \
               &dst[rr * 64 + (t & 7) * 8]);                                   \
    }                                                                          \
  }

// ---------------- 4-sub-phase BM=128 BN=128 GEMM: 64KB LDS -> 2 blocks/CU ----------------
// Race-free staging invariant (r9 lesson): every STG targets a buffer whose reads
// ENDED at a barrier before the STG issues. Verified passing in r10/r11/r13.
#define PH64(bf, q, STAGE_STMT, VMSTMT)                                        \
  {                                                                            \
    if ((q) == 0) {                                                            \
      _Pragma("unroll") for (int ni = 0; ni < 2; ++ni)                         \
      _Pragma("unroll") for (int kk = 0; kk < 2; ++kk)                         \
        bfrag[ni][kk] = *(const bh8*)(&Bs[bf][(wn * 32 + ni * 16 + (lane & 15)) * 64 + (((lane >> 4) + kk * 4) ^ (lane & 7)) * 8]); \
    }                                                                          \
    _Pragma("unroll") for (int j = 0; j < 2; ++j)                              \
    _Pragma("unroll") for (int kk = 0; kk < 2; ++kk)                           \
      af[j][kk] = *(const bh8*)(&As[bf][(wm * 64 + (2 * (q) + j) * 16 + (lane & 15)) * 64 + (((lane >> 4) + kk * 4) ^ (lane & 7)) * 8]); \
    STAGE_STMT;                                                                \
    __builtin_amdgcn_s_barrier();                                              \
    asm volatile("s_waitcnt lgkmcnt(0)" ::: "memory");                         \
    __builtin_amdgcn_sched_barrier(0);                                         \
    __builtin_amdgcn_s_setprio(1);                                             \
    _Pragma("unroll") for (int j = 0; j < 2; ++j)                              \
    _Pragma("unroll") for (int ni = 0; ni < 2; ++ni)                           \
    _Pragma("unroll") for (int kk = 0; kk < 2; ++kk)                           \
      acc[2 * (q) + j][ni] = __builtin_amdgcn_mfma_f32_16x16x32_bf16(          \
          af[j][kk], bfrag[ni][kk], acc[2 * (q) + j][ni], 0, 0, 0);            \
    __builtin_amdgcn_s_setprio(0);                                             \
    VMSTMT;                                                                    \
    __builtin_amdgcn_s_barrier();                                              \
  }

// QKVMODE: bn<16 -> q/k columns with fused RoPE (q additionally pre-scaled by
// 1/8 so flash softmax needs no scale); bn>=16 -> V stored transposed to Vt.
template <int RELU, int RES, int OBF16, int QKVMODE>
__global__ __launch_bounds__(512, 4)
void gemm_bn128(const short* __restrict__ A, const short* __restrict__ Bw,
                const float* __restrict__ bias, const float* __restrict__ res,
                const float* __restrict__ ct, const float* __restrict__ st,
                short* __restrict__ Vt,
                short* __restrict__ Cb, float* __restrict__ Cf,
                int M, int N, int K) {
  __shared__ short As[2][128 * 64];
  __shared__ short Bs[2][128 * 64];
  const int t = threadIdx.x, lane = t & 63;
  const int w = t >> 6, wm = w >> 2, wn = w & 3;
  const int nwg = gridDim.x, cpx = nwg >> 3;
  int flat = blockIdx.x;
  flat = (flat & 7) * cpx + (flat >> 3);
  const int nbn = N >> 7;
  const int bn = flat % nbn, bm = flat / nbn;   // bn-major: A panels XCD-local
  const short* Ab = A + (size_t)(bm * 128) * K;
  const short* Bb = Bw + (size_t)(bn * 128) * K;
  const int nkt = K >> 6;
  const int sr = t >> 3;
  const int ssl = (t & 7) ^ (sr & 7);
  f4 acc[4][2] = {};
  bh8 bfrag[2][2], af[2][2];

  // prologue: B0(2), A0(2), B1(2); VM2 drains B0,A0 (leaves B1)
  STG(Bs[0], Bb, 0, 0); STG(As[0], Ab, 0, 0);
  STG(Bs[1], Bb, 1, 0);
  VM2();
  __builtin_amdgcn_s_barrier();

  for (int i2 = 0; i2 < nkt; i2 += 2) {
    const bool nf = (i2 + 2 < nkt);
    PH64(0, 0, STG(As[1], Ab, i2 + 1, 0), );
    PH64(0, 1, if (nf) STG(Bs[0], Bb, i2 + 2, 0),
         if (nf) { VM2(); } else { VM0(); });
    PH64(1, 0, if (nf) STG(As[0], Ab, i2 + 2, 0), );
    PH64(1, 1, if (nf) STG(Bs[1], Bb, i2 + 3, 0), if (nf) { VM2(); });
  }

  const int rb = bm * 128 + wm * 64 + ((lane >> 4) << 2);
  const int cb = bn * 128 + wn * 32 + (lane & 15);
  if (QKVMODE && bn >= 16) {
    // V columns: transposed store into Vt[b,h,d,s] (4 s-consecutive per store)
#pragma unroll
    for (int mi = 0; mi < 4; ++mi) {
#pragma unroll
      for (int ni = 0; ni < 2; ++ni) {
        const int c = cb + ni * 16;
        const float bi = bias[c];
        const int hh = (c - 2048) >> 6, dd = (c - 2048) & 63;
        const int r0 = rb + mi * 16;
        const int bb2 = r0 >> 11, ss = r0 & 2047;
        sh4 pk;
#pragma unroll
        for (int jr = 0; jr < 4; ++jr) pk[jr] = (short)f2bf(acc[mi][ni][jr] + bi);
        *(sh4*)(Vt + ((size_t)(bb2 * 16 + hh) * 64 + dd) * 2048 + ss) = pk;
      }
    }
  } else if (QKVMODE) {
    // q/k columns: fused RoPE then bf16 store; q (bn<8) pre-scaled by 1/8
    const bool evenc = (lane & 1) == 0;
    const float qsc = (bn < 8) ? 0.125f : 1.0f;
#pragma unroll
    for (int mi = 0; mi < 4; ++mi) {
#pragma unroll
      for (int ni = 0; ni < 2; ++ni) {
        const int c = cb + ni * 16;
        const float bi = bias[c];
        const int j0 = (c & 63) >> 1;
#pragma unroll
        for (int jr = 0; jr < 4; ++jr) {
          const int r = rb + mi * 16 + jr;
          const int s = r & 2047;
          const float v = acc[mi][ni][jr] + bi;
          const float pv = __shfl_xor(v, 1, 64);   // partner column c^1, same row
          const float cs = ct[s * 32 + j0], sn = st[s * 32 + j0];
          const float o = (evenc ? (v * cs - pv * sn) : (pv * sn + v * cs)) * qsc;
          Cb[(size_t)r * N + c] = (short)f2bf(o);
        }
      }
    }
  } else {
#pragma unroll
    for (int mi = 0; mi < 4; ++mi) {
#pragma unroll
      for (int ni = 0; ni < 2; ++ni) {
        const int c = cb + ni * 16;
        const float bi = bias[c];
#pragma unroll
        for (int jr = 0; jr < 4; ++jr) {
          const int r = rb + mi * 16 + jr;
          float v = acc[mi][ni][jr] + bi;
          if (RES) v += res[(size_t)r * N + c];
          if (RELU) v = fmaxf(v, 0.f);
          if (OBF16) Cb[(size_t)r * N + c] = (short)f2bf(v);
          else       Cf[(size_t)r * N + c] = v;
        }
      }
    }
  }
}

// ---------------- 8-phase BM=256 BN=256 GEMM (r10-verified; used for FF1) ----------------
#define PH256(bf, q, STAGE_STMT, VMSTMT)                                       \
  {                                                                            \
    if ((q) == 0) {                                                            \
      _Pragma("unroll") for (int ni = 0; ni < 4; ++ni)                         \
      _Pragma("unroll") for (int kk = 0; kk < 2; ++kk)                         \
        bfrag[ni][kk] = *(const bh8*)(&Bs[bf][(wn * 64 + ni * 16 + (lane & 15)) * 64 + (((lane >> 4) + kk * 4) ^ (lane & 7)) * 8]); \
    }                                                                          \
    _Pragma("unroll") for (int j = 0; j < 2; ++j)                              \
    _Pragma("unroll") for (int kk = 0; kk < 2; ++kk)                           \
      af[j][kk] = *(const bh8*)(&As[bf][(wm * 128 + (2 * (q) + j) * 16 + (lane & 15)) * 64 + (((lane >> 4) + kk * 4) ^ (lane & 7)) * 8]); \
    STAGE_STMT;                                                                \
    __builtin_amdgcn_s_barrier();                                              \
    asm volatile("s_waitcnt lgkmcnt(0)" ::: "memory");                         \
    __builtin_amdgcn_sched_barrier(0);                                         \
    __builtin_amdgcn_s_setprio(1);                                             \
    _Pragma("unroll") for (int j = 0; j < 2; ++j)                              \
    _Pragma("unroll") for (int ni = 0; ni < 4; ++ni)                           \
    _Pragma("unroll") for (int kk = 0; kk < 2; ++kk)                           \
      acc[2 * (q) + j][ni] = __builtin_amdgcn_mfma_f32_16x16x32_bf16(          \
          af[j][kk], bfrag[ni][kk], acc[2 * (q) + j][ni], 0, 0, 0);            \
    __builtin_amdgcn_s_setprio(0);                                             \
    VMSTMT;                                                                    \
    __builtin_amdgcn_s_barrier();                                              \
  }

__global__ __launch_bounds__(512, 2)
void gemm256_ff1(const short* __restrict__ A, const short* __restrict__ Bw,
                 const float* __restrict__ bias, short* __restrict__ Cb,
                 int M, int N, int K) {
  __shared__ short As[2][256 * 64];
  __shared__ short Bs[2][256 * 64];
  const int t = threadIdx.x, lane = t & 63;
  const int w = t >> 6, wm = w >> 2, wn = w & 3;
  const int nwg = gridDim.x, cpx = nwg >> 3;
  int flat = blockIdx.x;
  flat = (flat & 7) * cpx + (flat >> 3);
  const int nbn = N >> 8;
  const int bn = flat % nbn, bm = flat / nbn;   // bn-major
  const short* Ab = A + (size_t)(bm * 256) * K;
  const short* Bb = Bw + (size_t)(bn * 256) * K;
  const int nkt = K >> 6;
  const int sr = t >> 3;
  const int ssl = (t & 7) ^ (sr & 7);
  f4 acc[8][4] = {};
  bh8 bfrag[4][2], af[2][2];

  STG(Bs[0], Bb, 0, 0); STG(Bs[0], Bb, 0, 1);
  STG(As[0], Ab, 0, 0); STG(As[0], Ab, 0, 1);
  STG(Bs[1], Bb, 1, 0); STG(Bs[1], Bb, 1, 1);
  VM4();
  __builtin_amdgcn_s_barrier();

  for (int i2 = 0; i2 < nkt; i2 += 2) {
    const bool nf = (i2 + 2 < nkt);
    PH256(0, 0, STG(As[1], Ab, i2 + 1, 0), );
    PH256(0, 1, STG(As[1], Ab, i2 + 1, 1), );
    PH256(0, 2, if (nf) STG(Bs[0], Bb, i2 + 2, 0), );
    PH256(0, 3, if (nf) STG(Bs[0], Bb, i2 + 2, 1),
          if (nf) { VM4(); } else { VM0(); });
    PH256(1, 0, if (nf) STG(As[0], Ab, i2 + 2, 0), );
    PH256(1, 1, if (nf) STG(As[0], Ab, i2 + 2, 1), );
    PH256(1, 2, if (nf) STG(Bs[1], Bb, i2 + 3, 0), );
    PH256(1, 3, if (nf) STG(Bs[1], Bb, i2 + 3, 1), if (nf) { VM4(); });
  }

  const int rb = bm * 256 + wm * 128 + ((lane >> 4) << 2);
  const int cb = bn * 256 + wn * 64 + (lane & 15);
#pragma unroll
  for (int mi = 0; mi < 8; ++mi) {
#pragma unroll
    for (int ni = 0; ni < 4; ++ni) {
      const int c = cb + ni * 16;
      const float bi = bias[c];
#pragma unroll
      for (int jr = 0; jr < 4; ++jr) {
        const int r = rb + mi * 16 + jr;
        Cb[(size_t)r * N + c] = (short)f2bf(fmaxf(acc[mi][ni][jr] + bi, 0.f));
      }
    }
  }
}

// ---------------- causal flash attention: 256-thr / 128-q-row blocks, 4/CU ----------------
// 4 warps x 32 q-rows, 32x32 MFMA, swapped QK^T, in-register softmax, defer-max,
// setprio around MFMA clusters (T5), tree-max (depth 5 vs 31-op chain).
__global__ __launch_bounds__(256, 4)
void flash_attn(const short* __restrict__ qkv, const short* __restrict__ vt,
                short* __restrict__ o) {
  __shared__ short lds[2 * 2 * 64 * 72];     // [buf][K|Vt][64][72]; reused as Ot[128][72]
  const int t = threadIdx.x, lane = t & 63, w = t >> 6;   // w 0..3
  const int l31 = lane & 31, l5 = lane >> 5;
  const int id = blockIdx.x;
  const int half = id >> 9, j = id & 511;
  const int xcd = j & 7, y = j >> 3;         // y 0..63
  const int bh = xcd * 8 + (y >> 3);
  const int pr = y & 7;
  const int qt = half ? pr : 15 - pr;        // 128-row q tile, 0..15
  const int b = bh >> 4, hh = bh & 15;
  const int r8 = t >> 3, c8 = (t & 7) * 8;   // r8 0..31
  const float NEG_INF = -__builtin_inff();

  const short* kbase = qkv + (size_t)b * 2048 * 3072 + 1024 + hh * 64;
  const short* vbase = vt + (size_t)bh * 64 * 2048;
  const int wq0 = qt * 128 + w * 32;
  const int nt = 2 * qt + 2;

  bh8 qf[4];
  {
    const short* qrow = qkv + ((size_t)b * 2048 + wq0 + l31) * 3072 + hh * 64 + l5 * 8;
#pragma unroll
    for (int dk = 0; dk < 4; ++dk) qf[dk] = *(const bh8*)(qrow + dk * 16);
  }
  f16v o0 = {}, o1 = {};
  float mr = NEG_INF, lsum = 0.f;

  bh8 rk[2], rv[2];
#pragma unroll
  for (int p = 0; p < 2; ++p) {
    rk[p] = *(const bh8*)(kbase + (size_t)(p * 32 + r8) * 3072 + c8);
    rv[p] = *(const bh8*)(vbase + (size_t)(p * 32 + r8) * 2048 + c8);
  }
#pragma unroll
  for (int p = 0; p < 2; ++p) {
    *(bh8*)(&lds[(p * 32 + r8) * 72 + c8]) = rk[p];
    *(bh8*)(&lds[4608 + (p * 32 + r8) * 72 + c8]) = rv[p];
  }

  for (int kt = 0; kt < nt; ++kt) {
    __syncthreads();
    const int cur = kt & 1, nxt = cur ^ 1;
    const bool more = (kt + 1 < nt);
    if (more) {                              // issue next tile's loads early (T14)
#pragma unroll
      for (int p = 0; p < 2; ++p) {
        rk[p] = *(const bh8*)(kbase + (size_t)((kt + 1) * 64 + p * 32 + r8) * 3072 + c8);
        rv[p] = *(const bh8*)(vbase + (size_t)(p * 32 + r8) * 2048 + (kt + 1) * 64 + c8);
      }
    }
    const int kvb = kt * 64;
    if (kvb <= wq0 + 31) {
      const short* Kl = &lds[cur * 9216];
      const short* Vl = &lds[cur * 9216 + 4608];
      f16v s0 = {}, s1 = {};
      __builtin_amdgcn_s_setprio(1);
#pragma unroll
      for (int dk = 0; dk < 4; ++dk) {
        bh8 ka0 = *(const bh8*)(&Kl[l31 * 72 + dk * 16 + l5 * 8]);
        bh8 ka1 = *(const bh8*)(&Kl[(32 + l31) * 72 + dk * 16 + l5 * 8]);
        s0 = __builtin_amdgcn_mfma_f32_32x32x16_bf16(ka0, qf[dk], s0, 0, 0, 0);
        s1 = __builtin_amdgcn_mfma_f32_32x32x16_bf16(ka1, qf[dk], s1, 0, 0, 0);
      }
      __builtin_amdgcn_s_setprio(0);
      if (kvb + 63 > wq0) {
        const int qq = wq0 + l31;
        const int kvo = kvb + l5 * 4;
#pragma unroll
        for (int r = 0; r < 16; ++r) {
          const int kv0 = kvo + (r & 3) + 8 * (r >> 2);
          if (kv0 > qq) s0[r] = NEG_INF;
          if (kv0 + 32 > qq) s1[r] = NEG_INF;
        }
      }
      // tree-max (depth 5) over the lane's 32 score values
      float tm[16];
#pragma unroll
      for (int r = 0; r < 16; ++r) tm[r] = fmaxf(s0[r], s1[r]);
#pragma unroll
      for (int off = 8; off >= 1; off >>= 1)
#pragma unroll
        for (int r = 0; r < 8; ++r)
          if (r < off) tm[r] = fmaxf(tm[r], tm[r + off]);
      float mx = tm[0];
      mx = fmaxf(mx, __shfl_xor(mx, 32, 64));
      const bool keep = __all(mx <= mr + 8.0f);   // T13 defer-max, THR=8 (scaled)
      float mn, al;
      if (keep) { mn = mr; al = 1.0f; }
      else {
        mn = fmaxf(mr, mx);
        al = __expf(mr - mn);
        mr = mn;
      }
      float rsA = 0.f, rsB = 0.f;
#pragma unroll
      for (int r = 0; r < 16; ++r) {
        const float p0 = __expf(s0[r] - mn);
        const float p1 = __expf(s1[r] - mn);
        s0[r] = p0; s1[r] = p1;
        rsA += p0; rsB += p1;
      }
      float rs = rsA + rsB;
      rs += __shfl_xor(rs, 32, 64);
      if (keep) {
        lsum += rs;
      } else {
        lsum = lsum * al + rs;
#pragma unroll
        for (int r = 0; r < 16; ++r) { o0[r] *= al; o1[r] *= al; }
      }
      float pp[32];
#pragma unroll
      for (int r = 0; r < 16; ++r) { pp[r] = s0[r]; pp[16 + r] = s1[r]; }
      const bool lo32 = (l5 == 0);
#pragma unroll
      for (int ks = 0; ks < 4; ++ks) {
        const int base = (ks >> 1) * 16 + (ks & 1) * 8;
        const unsigned e0 = cvtpk_bf16(pp[base + 0], pp[base + 1]);
        const unsigned e1 = cvtpk_bf16(pp[base + 2], pp[base + 3]);
        const unsigned q0 = cvtpk_bf16(pp[base + 4], pp[base + 5]);
        const unsigned q1 = cvtpk_bf16(pp[base + 6], pp[base + 7]);
        const unsigned sel0 = lo32 ? q0 : e0;
        const unsigned sel1 = lo32 ? q1 : e1;
        const unsigned rx0 = (unsigned)__shfl_xor((int)sel0, 32, 64);
        const unsigned rx1 = (unsigned)__shfl_xor((int)sel1, 32, 64);
        u4 frag;
        frag[0] = lo32 ? e0 : rx0;
        frag[1] = lo32 ? e1 : rx1;
        frag[2] = lo32 ? rx0 : q0;
        frag[3] = lo32 ? rx1 : q1;
        const bh8 pb = *(const bh8*)&frag;
        bh8 va0 = *(const bh8*)(&Vl[l31 * 72 + ks * 16 + l5 * 8]);
        bh8 va1 = *(const bh8*)(&Vl[(32 + l31) * 72 + ks * 16 + l5 * 8]);
        __builtin_amdgcn_s_setprio(1);
        o0 = __builtin_amdgcn_mfma_f32_32x32x16_bf16(va0, pb, o0, 0, 0, 0);
        o1 = __builtin_amdgcn_mfma_f32_32x32x16_bf16(va1, pb, o1, 0, 0, 0);
        __builtin_amdgcn_s_setprio(0);
      }
    }
    if (more) {
#pragma unroll
      for (int p = 0; p < 2; ++p) {
        *(bh8*)(&lds[nxt * 9216 + (p * 32 + r8) * 72 + c8]) = rk[p];
        *(bh8*)(&lds[nxt * 9216 + 4608 + (p * 32 + r8) * 72 + c8]) = rv[p];
      }
    }
  }

  const float inv = 1.0f / lsum;
  __syncthreads();
  short* Ot = lds;                            // [128][72]
#pragma unroll
  for (int r = 0; r < 16; ++r) {
    const int d = (r & 3) + 8 * (r >> 2) + 4 * l5;
    Ot[(w * 32 + l31) * 72 + d]      = (short)f2bf(o0[r] * inv);
    Ot[(w * 32 + l31) * 72 + 32 + d] = (short)f2bf(o1[r] * inv);
  }
  __syncthreads();
  const int qrow = t >> 1, hf = t & 1;        // 128 rows x 2 halves
  short* orow = o + ((size_t)b * 2048 + qt * 128 + qrow) * 1024 + hh * 64 + hf * 32;
#pragma unroll
  for (int i = 0; i < 4; ++i)
    *(bh8*)(orow + i * 8) = *(const bh8*)(&Ot[qrow * 72 + hf * 32 + i * 8]);
}

extern "C" void kernel_launch(void* const* d_in, const int* in_sizes, int n_in,
                              void* d_out, int out_size, void* d_ws, size_t ws_size,
                              hipStream_t stream) {
  const float* x   = (const float*)d_in[0];
  const float* Wq  = (const float*)d_in[1];
  const float* bq  = (const float*)d_in[2];
  const float* Wk  = (const float*)d_in[3];
  const float* bk  = (const float*)d_in[4];
  const float* Wv  = (const float*)d_in[5];
  const float* bv  = (const float*)d_in[6];
  const float* Wo  = (const float*)d_in[7];
  const float* bo  = (const float*)d_in[8];
  const float* W1  = (const float*)d_in[9];
  const float* bf1 = (const float*)d_in[10];
  const float* W2  = (const float*)d_in[11];
  const float* bf2 = (const float*)d_in[12];
  const float* g1  = (const float*)d_in[13];
  const float* be1 = (const float*)d_in[14];
  const float* g2  = (const float*)d_in[15];
  const float* be2 = (const float*)d_in[16];
  float* out = (float*)d_out;

  char* ws = (char*)d_ws;
  const size_t MB = 1u << 20;
  short* h_ob  = (short*)ws;                  // 16 MB: LN out; later attn out; later LN2 out
  short* qkv   = (short*)(ws + 16 * MB);      // 48 MB [8192][3072] (v-third unused)
  short* f1    = (short*)(ws + 16 * MB);      // 64 MB alias (qkv+vt, dead at FF time)
  short* vtb   = (short*)(ws + 64 * MB);      // 16 MB [bh][64][2048]
  short* wqkvb = (short*)(ws + 80 * MB);      // 6 MB
  short* wob   = (short*)(ws + 86 * MB);      // 2 MB
  short* w1b   = (short*)(ws + 88 * MB);      // 8 MB
  short* w2b   = (short*)(ws + 96 * MB);      // 8 MB
  float* ct    = (float*)(ws + 104 * MB);     // 256 KB
  float* st    = ct + 65536;                  // 256 KB
  float* bqkv  = st + 65536;                  // 12 KB
  float* x2    = out;

  prep_all<<<12556, 256, 0, stream>>>(Wq, Wk, Wv, Wo, W1, W2, bq, bk, bv,
                                      wqkvb, wob, w1b, w2b, ct, st, bqkv);

  layernorm_bf<<<8192, 256, 0, stream>>>(x, g1, be1, h_ob);

  // QKV: fused RoPE (q pre-scaled 1/8) + transposed V store; grid 64*24
  gemm_bn128<0, 0, 1, 1><<<1536, 512, 0, stream>>>(h_ob, wqkvb, bqkv, nullptr,
                                                   ct, st, vtb, qkv, nullptr,
                                                   8192, 3072, 1024);

  flash_attn<<<1024, 256, 0, stream>>>(qkv, vtb, h_ob);

  // Wo: +res, fp32 out; grid 64*8
  gemm_bn128<0, 1, 0, 0><<<512, 512, 0, stream>>>(h_ob, wob, bo, x,
                                                  nullptr, nullptr, nullptr,
                                                  nullptr, x2, 8192, 1024, 1024);

  layernorm_bf<<<8192, 256, 0, stream>>>(x2, g2, be2, h_ob);

  // FF1: 256^2 8-phase, relu, bf16 out; grid 32*16
  gemm256_ff1<<<512, 512, 0, stream>>>(h_ob, w1b, bf1, f1, 8192, 4096, 1024);

  // FF2: +res, fp32 out; grid 64*8
  gemm_bn128<0, 1, 0, 0><<<512, 512, 0, stream>>>(f1, w2b, bf2, x2,
                                                  nullptr, nullptr, nullptr,
                                                  nullptr, out, 8192, 1024, 4096);
}

// Round 15
// 344.788 us; speedup vs baseline: 1.1041x; 1.0143x over previous
//
#include <hip/hip_runtime.h>

typedef __attribute__((ext_vector_type(8))) short bh8;
typedef __attribute__((ext_vector_type(4))) short sh4;
typedef __attribute__((ext_vector_type(4))) float f4;
typedef __attribute__((ext_vector_type(16))) float f16v;
typedef __attribute__((ext_vector_type(4))) unsigned int u4;

__device__ __forceinline__ unsigned short f2bf(float x) {
  unsigned int u = __float_as_uint(x);
  u += 0x7fffu + ((u >> 16) & 1u);
  return (unsigned short)(u >> 16);
}
__device__ __forceinline__ float bf2f(short x) {
  return __uint_as_float(((unsigned int)(unsigned short)x) << 16);
}
__device__ __forceinline__ unsigned cvtpk_bf16(float lo, float hi) {
  unsigned r;
  asm("v_cvt_pk_bf16_f32 %0, %1, %2" : "=v"(r) : "v"(lo), "v"(hi));
  return r;
}
__device__ __forceinline__ void gl_lds16(const short* g, short* l) {
  __builtin_amdgcn_global_load_lds(
      (const __attribute__((address_space(1))) unsigned int*)g,
      (__attribute__((address_space(3))) unsigned int*)l, 16, 0, 0);
}

#define VM4() asm volatile("s_waitcnt vmcnt(4)" ::: "memory")
#define VM2() asm volatile("s_waitcnt vmcnt(2)" ::: "memory")
#define VM0() asm volatile("s_waitcnt vmcnt(0)" ::: "memory")

// ---------------- fused prologue: RoPE table + bias concat + all weight bf16 casts ----------------
__global__ __launch_bounds__(256)
void prep_all(const float* __restrict__ Wq, const float* __restrict__ Wk,
              const float* __restrict__ Wv, const float* __restrict__ Wo,
              const float* __restrict__ W1, const float* __restrict__ W2,
              const float* __restrict__ bq, const float* __restrict__ bk,
              const float* __restrict__ bv,
              short* __restrict__ wqkvb, short* __restrict__ wob,
              short* __restrict__ w1b, short* __restrict__ w2b,
              float* __restrict__ ct, float* __restrict__ st,
              float* __restrict__ bqkv) {
  const int t = threadIdx.x;
  int blk = blockIdx.x;
  if (blk < 256) {                    // rope cos/sin table (65536 entries)
    const int idx = blk * 256 + t;
    const int s = idx >> 5, j = idx & 31;
    const float invf = expf(-0.28782313662425574f * (float)j);  // 10000^(-j/32)
    const float f = (float)s * invf;
    ct[idx] = cosf(f);
    st[idx] = sinf(f);
    return;
  }
  blk -= 256;
  if (blk < 12) {                     // bias concat (3072 entries)
    const int i = blk * 256 + t;
    bqkv[i] = (i < 1024) ? bq[i] : ((i < 2048) ? bk[i - 1024] : bv[i - 2048]);
    return;
  }
  blk -= 12;
  const float* src; short* dst; int base;
  if (blk < 4096) {
    const int m = blk >> 10;
    src = (m == 0) ? Wq : (m == 1) ? Wk : (m == 2) ? Wv : Wo;
    dst = (m < 3) ? (wqkvb + (m << 20)) : wob;
    base = blk & 1023;
  } else if (blk < 8192) {
    src = W1; dst = w1b; base = blk - 4096;
  } else {
    src = W2; dst = w2b; base = blk - 8192;
  }
  const int i = (base * 256 + t) * 4;
  f4 v = *(const f4*)(src + i);
#pragma unroll
  for (int j = 0; j < 4; ++j) dst[i + j] = (short)f2bf(v[j]);
}

// ---------------- LayerNorm (row=1024) ----------------
__global__ __launch_bounds__(256)
void layernorm_bf(const float* __restrict__ x, const float* __restrict__ g,
                  const float* __restrict__ be, short* __restrict__ out) {
  __shared__ float sb[4];
  const int row = blockIdx.x, t = threadIdx.x;
  const float* xr = x + (size_t)row * 1024;
  f4 v = *(const f4*)(xr + t * 4);
  float s = v[0] + v[1] + v[2] + v[3];
#pragma unroll
  for (int mk = 1; mk < 64; mk <<= 1) s += __shfl_xor(s, mk, 64);
  if ((t & 63) == 0) sb[t >> 6] = s;
  __syncthreads();
  const float mean = (sb[0] + sb[1] + sb[2] + sb[3]) * (1.0f / 1024.0f);
  __syncthreads();
  f4 d;
#pragma unroll
  for (int i = 0; i < 4; ++i) d[i] = v[i] - mean;
  float s2 = d[0] * d[0] + d[1] * d[1] + d[2] * d[2] + d[3] * d[3];
#pragma unroll
  for (int mk = 1; mk < 64; mk <<= 1) s2 += __shfl_xor(s2, mk, 64);
  if ((t & 63) == 0) sb[t >> 6] = s2;
  __syncthreads();
  const float var = (sb[0] + sb[1] + sb[2] + sb[3]) * (1.0f / 1024.0f);
  const float rstd = rsqrtf(var + 1e-5f);
  const f4 gg = *(const f4*)(g + t * 4);
  const f4 bb = *(const f4*)(be + t * 4);
#pragma unroll
  for (int i = 0; i < 4; ++i)
    out[(size_t)row * 1024 + t * 4 + i] = (short)f2bf(d[i] * rstd * gg[i] + bb[i]);
}

// ================= shared staging macro =================
#define STG(dst, gbase, kt, half)                                              \
  {                                                                            \
    _Pragma("unroll") for (int cc = 0; cc < 2; ++cc) {                         \
      const int rr = (half) * 128 + cc * 64 + sr;                              \
      gl_lds16(gbase + (size_t)rr * K + (kt) * 64 + ssl * 8,                   \
               &dst[rr * 64 + (t & 7) * 8]);                                   \
    }                                                                          \
  }

// ---------------- 4-sub-phase BM=128 BN=128 GEMM: 64KB LDS -> 2 blocks/CU ----------------
// Race-free staging invariant (r9 lesson): every STG targets a buffer whose reads
// ENDED at a barrier before the STG issues. Verified passing r10-r14.
#define PH64(bf, q, STAGE_STMT, VMSTMT)                                        \
  {                                                                            \
    if ((q) == 0) {                                                            \
      _Pragma("unroll") for (int ni = 0; ni < 2; ++ni)                         \
      _Pragma("unroll") for (int kk = 0; kk < 2; ++kk)                         \
        bfrag[ni][kk] = *(const bh8*)(&Bs[bf][(wn * 32 + ni * 16 + (lane & 15)) * 64 + (((lane >> 4) + kk * 4) ^ (lane & 7)) * 8]); \
    }                                                                          \
    _Pragma("unroll") for (int j = 0; j < 2; ++j)                              \
    _Pragma("unroll") for (int kk = 0; kk < 2; ++kk)                           \
      af[j][kk] = *(const bh8*)(&As[bf][(wm * 64 + (2 * (q) + j) * 16 + (lane & 15)) * 64 + (((lane >> 4) + kk * 4) ^ (lane & 7)) * 8]); \
    STAGE_STMT;                                                                \
    __builtin_amdgcn_s_barrier();                                              \
    asm volatile("s_waitcnt lgkmcnt(0)" ::: "memory");                         \
    __builtin_amdgcn_sched_barrier(0);                                         \
    __builtin_amdgcn_s_setprio(1);                                             \
    _Pragma("unroll") for (int j = 0; j < 2; ++j)                              \
    _Pragma("unroll") for (int ni = 0; ni < 2; ++ni)                           \
    _Pragma("unroll") for (int kk = 0; kk < 2; ++kk)                           \
      acc[2 * (q) + j][ni] = __builtin_amdgcn_mfma_f32_16x16x32_bf16(          \
          af[j][kk], bfrag[ni][kk], acc[2 * (q) + j][ni], 0, 0, 0);            \
    __builtin_amdgcn_s_setprio(0);                                             \
    VMSTMT;                                                                    \
    __builtin_amdgcn_s_barrier();                                              \
  }

// QKVMODE: bn<16 -> q/k columns with fused RoPE (q pre-scaled 1/8); bn>=16 -> V
// stored transposed to Vt. XCD chunks: N==3072 -> 16bm x 12bn (square-ish, per-XCD
// unique 8->7MB); else bn-major (nbn=8 -> already 8x8).
template <int RELU, int RES, int OBF16, int QKVMODE>
__global__ __launch_bounds__(512, 4)
void gemm_bn128(const short* __restrict__ A, const short* __restrict__ Bw,
                const float* __restrict__ bias, const float* __restrict__ res,
                const float* __restrict__ ct, const float* __restrict__ st,
                short* __restrict__ Vt,
                short* __restrict__ Cb, float* __restrict__ Cf,
                int M, int N, int K) {
  __shared__ short As[2][128 * 64];
  __shared__ short Bs[2][128 * 64];
  const int t = threadIdx.x, lane = t & 63;
  const int w = t >> 6, wm = w >> 2, wn = w & 3;
  const int nwg = gridDim.x, cpx = nwg >> 3;
  int flat = blockIdx.x;
  flat = (flat & 7) * cpx + (flat >> 3);
  int bm, bn;
  if (N == 3072) {                     // 16x12 chunk per XCD (bijective over 64x24)
    const int xcd = flat / 192, i = flat % 192;
    bm = (xcd & 3) * 16 + i / 12;
    bn = (xcd >> 2) * 12 + i % 12;
  } else {                             // bn-major (nbn=8 -> 8x8 chunks)
    const int nbn = N >> 7;
    bn = flat % nbn; bm = flat / nbn;
  }
  const short* Ab = A + (size_t)(bm * 128) * K;
  const short* Bb = Bw + (size_t)(bn * 128) * K;
  const int nkt = K >> 6;
  const int sr = t >> 3;
  const int ssl = (t & 7) ^ (sr & 7);
  f4 acc[4][2] = {};
  bh8 bfrag[2][2], af[2][2];

  // prologue: B0(2), A0(2), B1(2); VM2 drains B0,A0 (leaves B1)
  STG(Bs[0], Bb, 0, 0); STG(As[0], Ab, 0, 0);
  STG(Bs[1], Bb, 1, 0);
  VM2();
  __builtin_amdgcn_s_barrier();

  for (int i2 = 0; i2 < nkt; i2 += 2) {
    const bool nf = (i2 + 2 < nkt);
    PH64(0, 0, STG(As[1], Ab, i2 + 1, 0), );
    PH64(0, 1, if (nf) STG(Bs[0], Bb, i2 + 2, 0),
         if (nf) { VM2(); } else { VM0(); });
    PH64(1, 0, if (nf) STG(As[0], Ab, i2 + 2, 0), );
    PH64(1, 1, if (nf) STG(Bs[1], Bb, i2 + 3, 0), if (nf) { VM2(); });
  }

  const int rb = bm * 128 + wm * 64 + ((lane >> 4) << 2);
  const int cb = bn * 128 + wn * 32 + (lane & 15);
  if (QKVMODE && bn >= 16) {
    // V columns: transposed store into Vt[b,h,d,s] (4 s-consecutive per store)
#pragma unroll
    for (int mi = 0; mi < 4; ++mi) {
#pragma unroll
      for (int ni = 0; ni < 2; ++ni) {
        const int c = cb + ni * 16;
        const float bi = bias[c];
        const int hh = (c - 2048) >> 6, dd = (c - 2048) & 63;
        const int r0 = rb + mi * 16;
        const int bb2 = r0 >> 11, ss = r0 & 2047;
        sh4 pk;
#pragma unroll
        for (int jr = 0; jr < 4; ++jr) pk[jr] = (short)f2bf(acc[mi][ni][jr] + bi);
        *(sh4*)(Vt + ((size_t)(bb2 * 16 + hh) * 64 + dd) * 2048 + ss) = pk;
      }
    }
  } else if (QKVMODE) {
    // q/k columns: fused RoPE then bf16 store; q (bn<8) pre-scaled by 1/8
    const bool evenc = (lane & 1) == 0;
    const float qsc = (bn < 8) ? 0.125f : 1.0f;
#pragma unroll
    for (int mi = 0; mi < 4; ++mi) {
#pragma unroll
      for (int ni = 0; ni < 2; ++ni) {
        const int c = cb + ni * 16;
        const float bi = bias[c];
        const int j0 = (c & 63) >> 1;
#pragma unroll
        for (int jr = 0; jr < 4; ++jr) {
          const int r = rb + mi * 16 + jr;
          const int s = r & 2047;
          const float v = acc[mi][ni][jr] + bi;
          const float pv = __shfl_xor(v, 1, 64);   // partner column c^1, same row
          const float cs = ct[s * 32 + j0], sn = st[s * 32 + j0];
          const float o = (evenc ? (v * cs - pv * sn) : (pv * sn + v * cs)) * qsc;
          Cb[(size_t)r * N + c] = (short)f2bf(o);
        }
      }
    }
  } else {
#pragma unroll
    for (int mi = 0; mi < 4; ++mi) {
#pragma unroll
      for (int ni = 0; ni < 2; ++ni) {
        const int c = cb + ni * 16;
        const float bi = bias[c];
#pragma unroll
        for (int jr = 0; jr < 4; ++jr) {
          const int r = rb + mi * 16 + jr;
          float v = acc[mi][ni][jr] + bi;
          if (RES) v += res[(size_t)r * N + c];
          if (RELU) v = fmaxf(v, 0.f);
          if (OBF16) Cb[(size_t)r * N + c] = (short)f2bf(v);
          else       Cf[(size_t)r * N + c] = v;
        }
      }
    }
  }
}

// ---------------- 8-phase BM=256 BN=256 GEMM (r10-verified; used for FF1) ----------------
#define PH256(bf, q, STAGE_STMT, VMSTMT)                                       \
  {                                                                            \
    if ((q) == 0) {                                                            \
      _Pragma("unroll") for (int ni = 0; ni < 4; ++ni)                         \
      _Pragma("unroll") for (int kk = 0; kk < 2; ++kk)                         \
        bfrag[ni][kk] = *(const bh8*)(&Bs[bf][(wn * 64 + ni * 16 + (lane & 15)) * 64 + (((lane >> 4) + kk * 4) ^ (lane & 7)) * 8]); \
    }                                                                          \
    _Pragma("unroll") for (int j = 0; j < 2; ++j)                              \
    _Pragma("unroll") for (int kk = 0; kk < 2; ++kk)                           \
      af[j][kk] = *(const bh8*)(&As[bf][(wm * 128 + (2 * (q) + j) * 16 + (lane & 15)) * 64 + (((lane >> 4) + kk * 4) ^ (lane & 7)) * 8]); \
    STAGE_STMT;                                                                \
    __builtin_amdgcn_s_barrier();                                              \
    asm volatile("s_waitcnt lgkmcnt(0)" ::: "memory");                         \
    __builtin_amdgcn_sched_barrier(0);                                         \
    __builtin_amdgcn_s_setprio(1);                                             \
    _Pragma("unroll") for (int j = 0; j < 2; ++j)                              \
    _Pragma("unroll") for (int ni = 0; ni < 4; ++ni)                           \
    _Pragma("unroll") for (int kk = 0; kk < 2; ++kk)                           \
      acc[2 * (q) + j][ni] = __builtin_amdgcn_mfma_f32_16x16x32_bf16(          \
          af[j][kk], bfrag[ni][kk], acc[2 * (q) + j][ni], 0, 0, 0);            \
    __builtin_amdgcn_s_setprio(0);                                             \
    VMSTMT;                                                                    \
    __builtin_amdgcn_s_barrier();                                              \
  }

__global__ __launch_bounds__(512, 2)
void gemm256_ff1(const short* __restrict__ A, const short* __restrict__ Bw,
                 const float* __restrict__ bias, short* __restrict__ Cb,
                 int M, int N, int K) {
  __shared__ short As[2][256 * 64];
  __shared__ short Bs[2][256 * 64];
  const int t = threadIdx.x, lane = t & 63;
  const int w = t >> 6, wm = w >> 2, wn = w & 3;
  const int nwg = gridDim.x, cpx = nwg >> 3;
  int flat = blockIdx.x;
  flat = (flat & 7) * cpx + (flat >> 3);
  // 8x8 chunk per XCD (bijective over 32bm x 16bn): per-XCD unique 10->8MB
  const int xcd = flat >> 6, i = flat & 63;
  const int bm = (xcd & 3) * 8 + (i >> 3);
  const int bn = (xcd >> 2) * 8 + (i & 7);
  const short* Ab = A + (size_t)(bm * 256) * K;
  const short* Bb = Bw + (size_t)(bn * 256) * K;
  const int nkt = K >> 6;
  const int sr = t >> 3;
  const int ssl = (t & 7) ^ (sr & 7);
  f4 acc[8][4] = {};
  bh8 bfrag[4][2], af[2][2];

  STG(Bs[0], Bb, 0, 0); STG(Bs[0], Bb, 0, 1);
  STG(As[0], Ab, 0, 0); STG(As[0], Ab, 0, 1);
  STG(Bs[1], Bb, 1, 0); STG(Bs[1], Bb, 1, 1);
  VM4();
  __builtin_amdgcn_s_barrier();

  for (int i2 = 0; i2 < nkt; i2 += 2) {
    const bool nf = (i2 + 2 < nkt);
    PH256(0, 0, STG(As[1], Ab, i2 + 1, 0), );
    PH256(0, 1, STG(As[1], Ab, i2 + 1, 1), );
    PH256(0, 2, if (nf) STG(Bs[0], Bb, i2 + 2, 0), );
    PH256(0, 3, if (nf) STG(Bs[0], Bb, i2 + 2, 1),
          if (nf) { VM4(); } else { VM0(); });
    PH256(1, 0, if (nf) STG(As[0], Ab, i2 + 2, 0), );
    PH256(1, 1, if (nf) STG(As[0], Ab, i2 + 2, 1), );
    PH256(1, 2, if (nf) STG(Bs[1], Bb, i2 + 3, 0), );
    PH256(1, 3, if (nf) STG(Bs[1], Bb, i2 + 3, 1), if (nf) { VM4(); });
  }

  const int rb = bm * 256 + wm * 128 + ((lane >> 4) << 2);
  const int cb = bn * 256 + wn * 64 + (lane & 15);
#pragma unroll
  for (int mi = 0; mi < 8; ++mi) {
#pragma unroll
    for (int ni = 0; ni < 4; ++ni) {
      const int c = cb + ni * 16;
      const float bi = bias[c];
#pragma unroll
      for (int jr = 0; jr < 4; ++jr) {
        const int r = rb + mi * 16 + jr;
        Cb[(size_t)r * N + c] = (short)f2bf(fmaxf(acc[mi][ni][jr] + bi, 0.f));
      }
    }
  }
}

// ---------------- causal flash attention: 256-thr / 128-q-row blocks, 4/CU ----------------
__global__ __launch_bounds__(256, 4)
void flash_attn(const short* __restrict__ qkv, const short* __restrict__ vt,
                short* __restrict__ o) {
  __shared__ short lds[2 * 2 * 64 * 72];     // [buf][K|Vt][64][72]; reused as Ot[128][72]
  const int t = threadIdx.x, lane = t & 63, w = t >> 6;   // w 0..3
  const int l31 = lane & 31, l5 = lane >> 5;
  const int id = blockIdx.x;
  const int half = id >> 9, j = id & 511;
  const int xcd = j & 7, y = j >> 3;         // y 0..63
  const int bh = xcd * 8 + (y >> 3);
  const int pr = y & 7;
  const int qt = half ? pr : 15 - pr;        // 128-row q tile, 0..15
  const int b = bh >> 4, hh = bh & 15;
  const int r8 = t >> 3, c8 = (t & 7) * 8;   // r8 0..31
  const float NEG_INF = -__builtin_inff();

  const short* kbase = qkv + (size_t)b * 2048 * 3072 + 1024 + hh * 64;
  const short* vbase = vt + (size_t)bh * 64 * 2048;
  const int wq0 = qt * 128 + w * 32;
  const int nt = 2 * qt + 2;

  bh8 qf[4];
  {
    const short* qrow = qkv + ((size_t)b * 2048 + wq0 + l31) * 3072 + hh * 64 + l5 * 8;
#pragma unroll
    for (int dk = 0; dk < 4; ++dk) qf[dk] = *(const bh8*)(qrow + dk * 16);
  }
  f16v o0 = {}, o1 = {};
  float mr = NEG_INF, lsum = 0.f;

  bh8 rk[2], rv[2];
#pragma unroll
  for (int p = 0; p < 2; ++p) {
    rk[p] = *(const bh8*)(kbase + (size_t)(p * 32 + r8) * 3072 + c8);
    rv[p] = *(const bh8*)(vbase + (size_t)(p * 32 + r8) * 2048 + c8);
  }
#pragma unroll
  for (int p = 0; p < 2; ++p) {
    *(bh8*)(&lds[(p * 32 + r8) * 72 + c8]) = rk[p];
    *(bh8*)(&lds[4608 + (p * 32 + r8) * 72 + c8]) = rv[p];
  }

  for (int kt = 0; kt < nt; ++kt) {
    __syncthreads();
    const int cur = kt & 1, nxt = cur ^ 1;
    const bool more = (kt + 1 < nt);
    if (more) {                              // issue next tile's loads early (T14)
#pragma unroll
      for (int p = 0; p < 2; ++p) {
        rk[p] = *(const bh8*)(kbase + (size_t)((kt + 1) * 64 + p * 32 + r8) * 3072 + c8);
        rv[p] = *(const bh8*)(vbase + (size_t)(p * 32 + r8) * 2048 + (kt + 1) * 64 + c8);
      }
    }
    const int kvb = kt * 64;
    if (kvb <= wq0 + 31) {
      const short* Kl = &lds[cur * 9216];
      const short* Vl = &lds[cur * 9216 + 4608];
      f16v s0 = {}, s1 = {};
      __builtin_amdgcn_s_setprio(1);
#pragma unroll
      for (int dk = 0; dk < 4; ++dk) {
        bh8 ka0 = *(const bh8*)(&Kl[l31 * 72 + dk * 16 + l5 * 8]);
        bh8 ka1 = *(const bh8*)(&Kl[(32 + l31) * 72 + dk * 16 + l5 * 8]);
        s0 = __builtin_amdgcn_mfma_f32_32x32x16_bf16(ka0, qf[dk], s0, 0, 0, 0);
        s1 = __builtin_amdgcn_mfma_f32_32x32x16_bf16(ka1, qf[dk], s1, 0, 0, 0);
      }
      __builtin_amdgcn_s_setprio(0);
      if (kvb + 63 > wq0) {
        const int qq = wq0 + l31;
        const int kvo = kvb + l5 * 4;
#pragma unroll
        for (int r = 0; r < 16; ++r) {
          const int kv0 = kvo + (r & 3) + 8 * (r >> 2);
          if (kv0 > qq) s0[r] = NEG_INF;
          if (kv0 + 32 > qq) s1[r] = NEG_INF;
        }
      }
      // tree-max (depth 5) over the lane's 32 score values
      float tm[16];
#pragma unroll
      for (int r = 0; r < 16; ++r) tm[r] = fmaxf(s0[r], s1[r]);
#pragma unroll
      for (int off = 8; off >= 1; off >>= 1)
#pragma unroll
        for (int r = 0; r < 8; ++r)
          if (r < off) tm[r] = fmaxf(tm[r], tm[r + off]);
      float mx = tm[0];
      mx = fmaxf(mx, __shfl_xor(mx, 32, 64));
      const bool keep = __all(mx <= mr + 8.0f);   // T13 defer-max, THR=8 (scaled)
      float mn, al;
      if (keep) { mn = mr; al = 1.0f; }
      else {
        mn = fmaxf(mr, mx);
        al = __expf(mr - mn);
        mr = mn;
      }
      float rsA = 0.f, rsB = 0.f;
#pragma unroll
      for (int r = 0; r < 16; ++r) {
        const float p0 = __expf(s0[r] - mn);
        const float p1 = __expf(s1[r] - mn);
        s0[r] = p0; s1[r] = p1;
        rsA += p0; rsB += p1;
      }
      float rs = rsA + rsB;
      rs += __shfl_xor(rs, 32, 64);
      if (keep) {
        lsum += rs;
      } else {
        lsum = lsum * al + rs;
#pragma unroll
        for (int r = 0; r < 16; ++r) { o0[r] *= al; o1[r] *= al; }
      }
      float pp[32];
#pragma unroll
      for (int r = 0; r < 16; ++r) { pp[r] = s0[r]; pp[16 + r] = s1[r]; }
      const bool lo32 = (l5 == 0);
#pragma unroll
      for (int ks = 0; ks < 4; ++ks) {
        const int base = (ks >> 1) * 16 + (ks & 1) * 8;
        const unsigned e0 = cvtpk_bf16(pp[base + 0], pp[base + 1]);
        const unsigned e1 = cvtpk_bf16(pp[base + 2], pp[base + 3]);
        const unsigned q0 = cvtpk_bf16(pp[base + 4], pp[base + 5]);
        const unsigned q1 = cvtpk_bf16(pp[base + 6], pp[base + 7]);
        const unsigned sel0 = lo32 ? q0 : e0;
        const unsigned sel1 = lo32 ? q1 : e1;
        const unsigned rx0 = (unsigned)__shfl_xor((int)sel0, 32, 64);
        const unsigned rx1 = (unsigned)__shfl_xor((int)sel1, 32, 64);
        u4 frag;
        frag[0] = lo32 ? e0 : rx0;
        frag[1] = lo32 ? e1 : rx1;
        frag[2] = lo32 ? rx0 : q0;
        frag[3] = lo32 ? rx1 : q1;
        const bh8 pb = *(const bh8*)&frag;
        bh8 va0 = *(const bh8*)(&Vl[l31 * 72 + ks * 16 + l5 * 8]);
        bh8 va1 = *(const bh8*)(&Vl[(32 + l31) * 72 + ks * 16 + l5 * 8]);
        __builtin_amdgcn_s_setprio(1);
        o0 = __builtin_amdgcn_mfma_f32_32x32x16_bf16(va0, pb, o0, 0, 0, 0);
        o1 = __builtin_amdgcn_mfma_f32_32x32x16_bf16(va1, pb, o1, 0, 0, 0);
        __builtin_amdgcn_s_setprio(0);
      }
    }
    if (more) {
#pragma unroll
      for (int p = 0; p < 2; ++p) {
        *(bh8*)(&lds[nxt * 9216 + (p * 32 + r8) * 72 + c8]) = rk[p];
        *(bh8*)(&lds[nxt * 9216 + 4608 + (p * 32 + r8) * 72 + c8]) = rv[p];
      }
    }
  }

  const float inv = 1.0f / lsum;
  __syncthreads();
  short* Ot = lds;                            // [128][72]
#pragma unroll
  for (int r = 0; r < 16; ++r) {
    const int d = (r & 3) + 8 * (r >> 2) + 4 * l5;
    Ot[(w * 32 + l31) * 72 + d]      = (short)f2bf(o0[r] * inv);
    Ot[(w * 32 + l31) * 72 + 32 + d] = (short)f2bf(o1[r] * inv);
  }
  __syncthreads();
  const int qrow = t >> 1, hf = t & 1;        // 128 rows x 2 halves
  short* orow = o + ((size_t)b * 2048 + qt * 128 + qrow) * 1024 + hh * 64 + hf * 32;
#pragma unroll
  for (int i = 0; i < 4; ++i)
    *(bh8*)(orow + i * 8) = *(const bh8*)(&Ot[qrow * 72 + hf * 32 + i * 8]);
}

extern "C" void kernel_launch(void* const* d_in, const int* in_sizes, int n_in,
                              void* d_out, int out_size, void* d_ws, size_t ws_size,
                              hipStream_t stream) {
  const float* x   = (const float*)d_in[0];
  const float* Wq  = (const float*)d_in[1];
  const float* bq  = (const float*)d_in[2];
  const float* Wk  = (const float*)d_in[3];
  const float* bk  = (const float*)d_in[4];
  const float* Wv  = (const float*)d_in[5];
  const float* bv  = (const float*)d_in[6];
  const float* Wo  = (const float*)d_in[7];
  const float* bo  = (const float*)d_in[8];
  const float* W1  = (const float*)d_in[9];
  const float* bf1 = (const float*)d_in[10];
  const float* W2  = (const float*)d_in[11];
  const float* bf2 = (const float*)d_in[12];
  const float* g1  = (const float*)d_in[13];
  const float* be1 = (const float*)d_in[14];
  const float* g2  = (const float*)d_in[15];
  const float* be2 = (const float*)d_in[16];
  float* out = (float*)d_out;

  char* ws = (char*)d_ws;
  const size_t MB = 1u << 20;
  short* h_ob  = (short*)ws;                  // 16 MB: LN out; later attn out; later LN2 out
  short* qkv   = (short*)(ws + 16 * MB);      // 48 MB [8192][3072] (v-third unused)
  short* f1    = (short*)(ws + 16 * MB);      // 64 MB alias (qkv+vt, dead at FF time)
  short* vtb   = (short*)(ws + 64 * MB);      // 16 MB [bh][64][2048]
  short* wqkvb = (short*)(ws + 80 * MB);      // 6 MB
  short* wob   = (short*)(ws + 86 * MB);      // 2 MB
  short* w1b   = (short*)(ws + 88 * MB);      // 8 MB
  short* w2b   = (short*)(ws + 96 * MB);      // 8 MB
  float* ct    = (float*)(ws + 104 * MB);     // 256 KB
  float* st    = ct + 65536;                  // 256 KB
  float* bqkv  = st + 65536;                  // 12 KB
  float* x2    = out;

  prep_all<<<12556, 256, 0, stream>>>(Wq, Wk, Wv, Wo, W1, W2, bq, bk, bv,
                                      wqkvb, wob, w1b, w2b, ct, st, bqkv);

  layernorm_bf<<<8192, 256, 0, stream>>>(x, g1, be1, h_ob);

  // QKV: fused RoPE (q pre-scaled 1/8) + transposed V store; grid 64*24
  gemm_bn128<0, 0, 1, 1><<<1536, 512, 0, stream>>>(h_ob, wqkvb, bqkv, nullptr,
                                                   ct, st, vtb, qkv, nullptr,
                                                   8192, 3072, 1024);

  flash_attn<<<1024, 256, 0, stream>>>(qkv, vtb, h_ob);

  // Wo: +res, fp32 out; grid 64*8
  gemm_bn128<0, 1, 0, 0><<<512, 512, 0, stream>>>(h_ob, wob, bo, x,
                                                  nullptr, nullptr, nullptr,
                                                  nullptr, x2, 8192, 1024, 1024);

  layernorm_bf<<<8192, 256, 0, stream>>>(x2, g2, be2, h_ob);

  // FF1: 256^2 8-phase, relu, bf16 out; grid 32*16
  gemm256_ff1<<<512, 512, 0, stream>>>(h_ob, w1b, bf1, f1, 8192, 4096, 1024);

  // FF2: +res, fp32 out; grid 64*8
  gemm_bn128<0, 1, 0, 0><<<512, 512, 0, stream>>>(f1, w2b, bf2, x2,
                                                  nullptr, nullptr, nullptr,
                                                  nullptr, out, 8192, 1024, 4096);
}